// Round 12
// baseline (3622.070 us; speedup 1.0000x reference)
//
#include <hip/hip_runtime.h>
#include <cstdint>
#include <cstddef>

#define B_ 128
#define P_ 196
#define ENC_ 2048
#define A_ 512
#define E_ 512
#define D_ 512
#define V_ 10000
#define L_ 52
#define T_ 51
#define ZPRE 8   // split-K slices for pre2 GEMM (K=512 -> 64/slice, 1 BK64 iter)
#define ZG 8     // split-K slices for gates-x GEMM (K=2560 -> 320/slice, 5 iters)
#define PLD 4608 // ppart row width: [pre 2560 | hh 2048]

using short8 = __attribute__((ext_vector_type(8))) short;
using short4v = __attribute__((ext_vector_type(4))) short;
using floatx4 = __attribute__((ext_vector_type(4))) float;

__device__ __forceinline__ float sigf(float x){ return 1.f/(1.f+expf(-x)); }

__device__ __forceinline__ unsigned short f2bf(float f){
  unsigned int u = __float_as_uint(f);
  unsigned int r = (u + 0x7fffu + ((u >> 16) & 1u)) >> 16;
  return (unsigned short)r;
}
__device__ __forceinline__ float bf2f(unsigned short u){
  return __uint_as_float(((unsigned int)u) << 16);
}

// ---------------- sort (stable descending by length) ----------------
__global__ void sort_kernel(const int* __restrict__ cap_len, const int* __restrict__ caps,
                            int* __restrict__ order, int* __restrict__ dec_len,
                            int* __restrict__ caps_sorted,
                            float* __restrict__ out_caps, float* __restrict__ out_declen){
  __shared__ int len_s[B_];
  int i = threadIdx.x;
  len_s[i] = cap_len[i];
  __syncthreads();
  int li = len_s[i];
  int pos = 0;
  for (int j = 0; j < B_; j++){
    int lj = len_s[j];
    pos += (lj > li) || (lj == li && j < i);
  }
  order[pos] = i;
  dec_len[pos] = li - 1;
  out_declen[pos] = (float)(li - 1);
  for (int l = 0; l < L_; l++){
    int v = caps[i * L_ + l];
    caps_sorted[pos * L_ + l] = v;
    out_caps[pos * L_ + l] = (float)v;
  }
}

// ---------------- enc gather + fp32->bf16 ----------------
__global__ void gather_kernel(const float* __restrict__ enc, const int* __restrict__ order,
                              unsigned short* __restrict__ enc_s){
  int b = blockIdx.y;
  int i = (blockIdx.x * 256 + threadIdx.x) * 4;
  const float4 v = *(const float4*)(enc + (size_t)order[b] * (P_ * ENC_) + i);
  short4v r;
  r[0] = (short)f2bf(v.x); r[1] = (short)f2bf(v.y);
  r[2] = (short)f2bf(v.z); r[3] = (short)f2bf(v.w);
  *(short4v*)(enc_s + (size_t)b * (P_ * ENC_) + i) = r;
}

// ---------------- weight conversion/packing + state init ----------------
__global__ void prep_kernel(const float* __restrict__ We, const float* __restrict__ Wd,
                            const float* __restrict__ Wbeta,
                            const float* __restrict__ W_ih, const float* __restrict__ W_hh,
                            const float* __restrict__ Wfc,
                            const float* __restrict__ bd, const float* __restrict__ bbeta,
                            const float* __restrict__ b_ih, const float* __restrict__ b_hh,
                            unsigned short* __restrict__ We_b, unsigned short* __restrict__ Wpre2_b,
                            unsigned short* __restrict__ Wg_b, unsigned short* __restrict__ Wfc_b,
                            float* __restrict__ bias_pre, float* __restrict__ bias_g,
                            float* __restrict__ h, float* __restrict__ c,
                            unsigned short* __restrict__ h_b){
  unsigned int idx = blockIdx.x * blockDim.x + threadIdx.x;
  unsigned int stride = gridDim.x * blockDim.x;
  // We_b: 512x2048 direct
  for (unsigned int i = idx; i < 512u * 2048u; i += stride) We_b[i] = f2bf(We[i]);
  // Wpre2_b = [Wd(512) ; Wbeta(2048) ; W_hh(2048)] x K=512
  for (unsigned int i = idx; i < 4608u * 512u; i += stride){
    unsigned int row = i >> 9, k = i & 511u;
    float v;
    if (row < 512u) v = Wd[row * 512u + k];
    else if (row < 2560u) v = Wbeta[(row - 512u) * 512u + k];
    else v = W_hh[(size_t)(row - 2560u) * 512u + k];
    Wpre2_b[i] = f2bf(v);
  }
  // Wg_b: W_ih direct (2048 x 2560)
  for (unsigned int i = idx; i < 2048u * 2560u; i += stride) Wg_b[i] = f2bf(W_ih[i]);
  // Wfc_b: 10000x512 direct
  for (unsigned int i = idx; i < 10000u * 512u; i += stride) Wfc_b[i] = f2bf(Wfc[i]);
  // biases
  for (unsigned int i = idx; i < 2560u; i += stride) bias_pre[i] = (i < 512u) ? bd[i] : bbeta[i - 512u];
  for (unsigned int i = idx; i < 2048u; i += stride) bias_g[i] = b_ih[i] + b_hh[i];
  // state init
  for (unsigned int i = idx; i < (unsigned)B_ * D_; i += stride){
    h[i] = 0.f; c[i] = 0.f; h_b[i] = 0;
  }
}

// ---------------- 256-thread GEMM core BK=32, XOR-swizzled LDS ---------------
#define GEMM_CORE(Aptr, LDA, Bptr, LDB, KDIM, NCLAMP)                         \
  int tid = threadIdx.x; int lane = tid & 63; int w = tid >> 6;               \
  const floatx4 vzero = {0.f,0.f,0.f,0.f};                                    \
  floatx4 acc[4][4];                                                          \
  _Pragma("unroll") for (int i_=0;i_<4;i_++)                                  \
  _Pragma("unroll") for (int j_=0;j_<4;j_++) acc[i_][j_]=vzero;               \
  int mbase=(w&1)<<6, nbase=(w>>1)<<6;                                        \
  int fr=lane&15, fk=(lane>>4)<<3;                                            \
  int rsw_ = (fr&3)<<3;                                                       \
  for (int k0=0;k0<(KDIM);k0+=32){                                            \
    _Pragma("unroll") for (int r_=0;r_<2;r_++){                               \
      int chunk=r_*256+tid; int row=chunk>>2, kc=(chunk&3)<<3;                \
      short8 av=*(const short8*)((Aptr)+(size_t)(m0+row)*(LDA)+k0+kc);        \
      int bn=n0+row; if(bn>(NCLAMP)) bn=(NCLAMP);                             \
      short8 bv=*(const short8*)((Bptr)+(size_t)bn*(LDB)+k0+kc);              \
      int sidx = row*32 + (kc ^ ((row&3)<<3));                                \
      *(short8*)&As[sidx]=av; *(short8*)&Bs[sidx]=bv; }                       \
    __syncthreads();                                                          \
    short8 af[4], bfrag[4];                                                   \
    _Pragma("unroll") for (int i_=0;i_<4;i_++){                               \
      af[i_]=*(const short8*)&As[(mbase+i_*16+fr)*32+(fk^rsw_)];              \
      bfrag[i_]=*(const short8*)&Bs[(nbase+i_*16+fr)*32+(fk^rsw_)]; }         \
    _Pragma("unroll") for (int mi_=0;mi_<4;mi_++)                             \
    _Pragma("unroll") for (int ni_=0;ni_<4;ni_++)                             \
      acc[mi_][ni_]=__builtin_amdgcn_mfma_f32_16x16x32_bf16(af[mi_],bfrag[ni_],acc[mi_][ni_],0,0,0); \
    __syncthreads(); }

// ---------------- generic GEMM (epi 1: bf16+bias) ----------------
__launch_bounds__(256)
__global__ void gemm_bf16(const unsigned short* __restrict__ A, int lda,
                          const unsigned short* __restrict__ Bm, int ldb,
                          const float* __restrict__ bias,
                          unsigned short* __restrict__ Cb, int ldc,
                          int N, int ksz)
{
  __shared__ unsigned short As[128 * 32];
  __shared__ unsigned short Bs[128 * 32];
  int m0 = blockIdx.y * 128, n0 = blockIdx.x * 128;
  GEMM_CORE(A, lda, Bm, ldb, ksz, N - 1)
#pragma unroll
  for (int mi = 0; mi < 4; mi++)
#pragma unroll
    for (int ni = 0; ni < 4; ni++){
      floatx4 v = acc[mi][ni];
      int col = n0 + nbase + ni * 16 + fr;
      int rb = m0 + mbase + mi * 16 + ((lane >> 4) << 2);
      float bb = bias[col];
#pragma unroll
      for (int r = 0; r < 4; r++)
        Cb[(size_t)(rb + r) * ldc + col] = f2bf(v[r] + bb);
    }
}

// ---------------- skinny GEMM: M=128, BK=64, XOR-swizzled, split-K stores ----
__launch_bounds__(256)
__global__ void gemm_skinny(const unsigned short* __restrict__ A, int lda,
                            const unsigned short* __restrict__ Bm, int ldb,
                            float* __restrict__ Cf, int ldc, int ksz)
{
  __shared__ unsigned short As[128 * 64];
  __shared__ unsigned short Bs[128 * 64];
  int tid = threadIdx.x; int lane = tid & 63; int w = tid >> 6;
  const floatx4 vzero = {0.f,0.f,0.f,0.f};
  floatx4 acc[4][4];
#pragma unroll
  for (int i_ = 0; i_ < 4; i_++)
#pragma unroll
    for (int j_ = 0; j_ < 4; j_++) acc[i_][j_] = vzero;
  int mbase = (w & 1) << 6, nbase = (w >> 1) << 6;
  int fr = lane & 15, fk = (lane >> 4) << 3;
  int rsw = (fr & 7) << 3;
  int n0 = blockIdx.x * 128;
  int kb = blockIdx.z * ksz;
  const unsigned short* Ap = A + kb;
  const unsigned short* Bp = Bm + kb;
  for (int k0 = 0; k0 < ksz; k0 += 64){
#pragma unroll
    for (int r_ = 0; r_ < 4; r_++){
      int chunk = r_ * 256 + tid;
      int row = chunk >> 3, kc = (chunk & 7) << 3;
      short8 av = *(const short8*)(Ap + (size_t)row * lda + k0 + kc);
      short8 bv = *(const short8*)(Bp + (size_t)(n0 + row) * ldb + k0 + kc);
      int sidx = row * 64 + (kc ^ ((row & 7) << 3));
      *(short8*)&As[sidx] = av;
      *(short8*)&Bs[sidx] = bv;
    }
    __syncthreads();
#pragma unroll
    for (int ks = 0; ks < 2; ks++){
      short8 af[4], bfrag[4];
#pragma unroll
      for (int i_ = 0; i_ < 4; i_++){
        int ra = mbase + i_ * 16 + fr;
        int rb2 = nbase + i_ * 16 + fr;
        af[i_]    = *(const short8*)&As[ra  * 64 + ((ks * 32 + fk) ^ rsw)];
        bfrag[i_] = *(const short8*)&Bs[rb2 * 64 + ((ks * 32 + fk) ^ rsw)];
      }
#pragma unroll
      for (int mi = 0; mi < 4; mi++)
#pragma unroll
        for (int ni = 0; ni < 4; ni++)
          acc[mi][ni] = __builtin_amdgcn_mfma_f32_16x16x32_bf16(af[mi], bfrag[ni], acc[mi][ni], 0, 0, 0);
    }
    __syncthreads();
  }
  float* Cz = Cf + (size_t)blockIdx.z * ((size_t)B_ * ldc);
#pragma unroll
  for (int mi = 0; mi < 4; mi++)
#pragma unroll
    for (int ni = 0; ni < 4; ni++){
      floatx4 v = acc[mi][ni];
      int col = n0 + nbase + ni * 16 + fr;
      int rb = mbase + mi * 16 + ((lane >> 4) << 2);
#pragma unroll
      for (int r = 0; r < 4; r++)
        Cz[(size_t)(rb + r) * ldc + col] = v[r];
    }
}

// ---------------- fused attention: scores + softmax + awe + gate -> xh ------
// grid (2, 128) x 1024 threads (round-8 verified structure; ppart ldc=4608).
__launch_bounds__(1024)
__global__ void attn_kernel(const unsigned short* __restrict__ enc_att,
                            const unsigned short* __restrict__ enc_s,
                            const float* __restrict__ ppart,      // [ZPRE][128][PLD]
                            const float* __restrict__ bias_pre,
                            const float* __restrict__ wf, const float* __restrict__ bfp,
                            const float* __restrict__ emb, const int* __restrict__ caps_sorted,
                            unsigned short* __restrict__ xh,      // [128][2560] = [emb|awe]
                            int t){
  __shared__ float sc[P_];
  __shared__ float al[P_];
  __shared__ float red[256];
  __shared__ float part2[8][128][8];   // 32 KB
  int b = blockIdx.y, bx = blockIdx.x, tid = threadIdx.x;

  // ---- phase 1: scores ----
  int wid = tid >> 6, lane = tid & 63;
  float dav[8], wfv[8];
  {
    const float* bp = bias_pre + lane * 8;
    const float* p0 = ppart + (size_t)b * PLD + lane * 8;
#pragma unroll
    for (int j = 0; j < 8; j++){
      float s = bp[j];
#pragma unroll
      for (int z = 0; z < ZPRE; z++) s += p0[(size_t)z * (B_ * PLD) + j];
      dav[j] = s;
    }
    *(float4*)&wfv[0] = *(const float4*)(wf + lane * 8);
    *(float4*)&wfv[4] = *(const float4*)(wf + lane * 8 + 4);
  }
  float bfv = bfp[0];
  for (int p = wid; p < P_; p += 16){
    short8 e = *(const short8*)(enc_att + ((size_t)b * P_ + p) * A_ + lane * 8);
    float s = 0.f;
#pragma unroll
    for (int j = 0; j < 8; j++){
      float v = bf2f((unsigned short)e[j]) + dav[j];
      s += fmaxf(v, 0.f) * wfv[j];
    }
#pragma unroll
    for (int off = 32; off > 0; off >>= 1) s += __shfl_down(s, off);
    if (lane == 0) sc[p] = s + bfv;
  }
  __syncthreads();

  // ---- phase 2: softmax over 196 ----
  if (tid < 256) red[tid] = (tid < P_) ? sc[tid] : -1e30f;
  __syncthreads();
  for (int s = 128; s > 0; s >>= 1){ if (tid < s) red[tid] = fmaxf(red[tid], red[tid + s]); __syncthreads(); }
  float mx = red[0];
  __syncthreads();
  float ex = 0.f;
  if (tid < 256){ ex = (tid < P_) ? expf(sc[tid] - mx) : 0.f; red[tid] = ex; }
  __syncthreads();
  for (int s = 128; s > 0; s >>= 1){ if (tid < s) red[tid] += red[tid + s]; __syncthreads(); }
  float inv = 1.f / red[0];
  if (tid < P_) al[tid] = ex * inv;
  __syncthreads();

  // ---- phase 3: awe with 8-way p split, 16B loads ----
  int pg = tid >> 7, et = tid & 127;
  int e0 = bx * 1024 + et * 8;
  const unsigned short* encb = enc_s + (size_t)b * (P_ * ENC_) + e0;
  float aa[8];
#pragma unroll
  for (int j = 0; j < 8; j++) aa[j] = 0.f;
  int pbeg = (pg * 196) >> 3, pend = ((pg + 1) * 196) >> 3;
#pragma unroll 5
  for (int p = pbeg; p < pend; p++){
    float a = al[p];
    short8 v = *(const short8*)(encb + (size_t)p * ENC_);
#pragma unroll
    for (int j = 0; j < 8; j++)
      aa[j] += a * bf2f((unsigned short)v[j]);
  }
#pragma unroll
  for (int j = 0; j < 8; j++) part2[pg][et][j] = aa[j];
  __syncthreads();
  if (pg == 0){
    float s[8];
#pragma unroll
    for (int j = 0; j < 8; j++){
      float acc = 0.f;
#pragma unroll
      for (int g = 0; g < 8; g++) acc += part2[g][et][j];
      s[j] = acc;
    }
    const float* bp = bias_pre + 512 + e0;
    const float* p0 = ppart + (size_t)b * PLD + 512 + e0;
    short8 r;
#pragma unroll
    for (int j = 0; j < 8; j++){
      float g = bp[j];
#pragma unroll
      for (int z = 0; z < ZPRE; z++) g += p0[(size_t)z * (B_ * PLD) + j];
      r[j] = (short)f2bf(sigf(g) * s[j]);
    }
    *(short8*)(xh + (size_t)b * 2560 + 512 + e0) = r;
  }
  // emb gather for this step's token into xh[:512]
  if (bx == 1 && tid < 512){
    int tok = caps_sorted[b * L_ + t];
    xh[(size_t)b * 2560 + tid] = f2bf(emb[(size_t)tok * E_ + tid]);
  }
}

// ---------------- LSTM pointwise: gates = Σz gpart[z] + Σz ppart_hh[z] + bias_g
__global__ void lstm_kernel(const float* __restrict__ gpart,   // [ZG][128][2048]
                            const float* __restrict__ ppart,   // [ZPRE][128][PLD], hh at 2560+
                            const float* __restrict__ bias_g,
                            float* __restrict__ h, float* __restrict__ c,
                            unsigned short* __restrict__ h_b,
                            unsigned short* __restrict__ hnew_b,
                            const int* __restrict__ dec_len, int t){
  int idx = blockIdx.x * 256 + threadIdx.x;   // 65536 total
  int b = idx >> 9, d = idx & 511;
  const float* gr = gpart + (size_t)b * 2048;
  const float* pr = ppart + (size_t)b * PLD + 2560;
  float i_ = bias_g[d], f_ = bias_g[512 + d], g_ = bias_g[1024 + d], o_ = bias_g[1536 + d];
#pragma unroll
  for (int z = 0; z < ZG; z++){
    const float* gz = gr + (size_t)z * (B_ * 2048);
    i_ += gz[d]; f_ += gz[512 + d]; g_ += gz[1024 + d]; o_ += gz[1536 + d];
  }
#pragma unroll
  for (int z = 0; z < ZPRE; z++){
    const float* pz = pr + (size_t)z * (B_ * PLD);
    i_ += pz[d]; f_ += pz[512 + d]; g_ += pz[1024 + d]; o_ += pz[1536 + d];
  }
  float cn = sigf(f_) * c[idx] + sigf(i_) * tanhf(g_);
  float hn = sigf(o_) * tanhf(cn);
  bool act = t < dec_len[b];
  float hv = act ? hn : h[idx];
  float cv = act ? cn : c[idx];
  h[idx] = hv; c[idx] = cv;
  h_b[idx] = f2bf(hv);
  hnew_b[(size_t)t * (B_ * D_) + idx] = f2bf(hn);
}

// ---------------- preds GEMM: XCD-rect partition + LDS-staged stores ---------
__launch_bounds__(256)
__global__ void gemm_preds(const unsigned short* __restrict__ A,    // hnew_b 6528x512
                           const unsigned short* __restrict__ Bm,   // Wfc_b 10000x512
                           const float* __restrict__ bias,
                           float* __restrict__ Cf,
                           const int* __restrict__ dec_len){
  __shared__ __attribute__((aligned(16))) char smem[4 * 64 * 68 * 4];
  unsigned short* As = (unsigned short*)smem;
  unsigned short* Bs = (unsigned short*)(smem + 8192);
  int bid = blockIdx.x;
  int xcd = bid & 7, i = bid >> 3;          // i in [0,520)
  int mchunk = xcd >> 1, nchunk = xcd & 1;
  int mi_ = i % 13, ni_ = i / 13;
  int mt = mchunk * 13 + mi_;
  int nt = nchunk * 40 + ni_;
  if (mt >= 51 || nt >= 79) return;
  int m0 = mt * 128, n0 = nt * 128;
  GEMM_CORE(A, D_, Bm, D_, D_, V_ - 1)
  float* Cs = (float*)smem + (size_t)w * (64 * 68);
#pragma unroll
  for (int mi = 0; mi < 4; mi++)
#pragma unroll
    for (int ni = 0; ni < 4; ni++){
      int lc = ni * 16 + fr;
      int col = n0 + nbase + lc;
      float bb = bias[col < V_ ? col : V_ - 1];
#pragma unroll
      for (int r = 0; r < 4; r++){
        int lr = mi * 16 + ((lane >> 4) << 2) + r;
        Cs[lr * 68 + lc] = acc[mi][ni][r] + bb;
      }
    }
#pragma unroll
  for (int rd = 0; rd < 16; rd++){
    int lr = rd * 4 + (lane >> 4);
    int m = m0 + mbase + lr;
    int tt = m >> 7, b = m & 127;
    int col = n0 + nbase + fr * 4;
    floatx4 v = *(const floatx4*)&Cs[lr * 68 + fr * 4];
    if (tt >= dec_len[b]){ v[0] = 0.f; v[1] = 0.f; v[2] = 0.f; v[3] = 0.f; }
    if (col < V_)
      __builtin_nontemporal_store(v, (floatx4*)(Cf + ((size_t)b * T_ + tt) * V_ + col));
  }
}

extern "C" void kernel_launch(void* const* d_in, const int* in_sizes, int n_in,
                              void* d_out, int out_size, void* d_ws, size_t ws_size,
                              hipStream_t stream) {
  const float* encoder_out = (const float*)d_in[0];
  const int*   caps        = (const int*)d_in[1];
  const int*   cap_len     = (const int*)d_in[2];
  const float* emb         = (const float*)d_in[3];
  const float* We          = (const float*)d_in[4];
  const float* be          = (const float*)d_in[5];
  const float* Wd          = (const float*)d_in[6];
  const float* bd          = (const float*)d_in[7];
  const float* wf          = (const float*)d_in[8];
  const float* bf          = (const float*)d_in[9];
  const float* W_ih        = (const float*)d_in[10];
  const float* b_ih        = (const float*)d_in[11];
  const float* W_hh        = (const float*)d_in[12];
  const float* b_hh        = (const float*)d_in[13];
  const float* Wbeta       = (const float*)d_in[14];
  const float* bbeta       = (const float*)d_in[15];
  const float* Wfc         = (const float*)d_in[16];
  const float* bfc         = (const float*)d_in[17];

  float* out_preds  = (float*)d_out;
  float* out_caps   = out_preds + (size_t)B_ * T_ * V_;
  float* out_declen = out_caps + (size_t)B_ * L_;

  char* w = (char*)d_ws;
  auto alloc = [&](size_t bytes) -> void* {
    void* p = (void*)w;
    w += (bytes + 255) & ~(size_t)255;
    return p;
  };
  int*   order       = (int*)alloc(B_ * 4);
  int*   dec_len     = (int*)alloc(B_ * 4);
  int*   caps_sorted = (int*)alloc((size_t)B_ * L_ * 4);
  unsigned short* enc_s   = (unsigned short*)alloc((size_t)B_ * P_ * ENC_ * 2);
  unsigned short* We_b    = (unsigned short*)alloc((size_t)512 * 2048 * 2);
  unsigned short* Wpre2_b = (unsigned short*)alloc((size_t)4608 * 512 * 2);
  unsigned short* Wg_b    = (unsigned short*)alloc((size_t)2048 * 2560 * 2);
  unsigned short* Wfc_b   = (unsigned short*)alloc((size_t)10000 * 512 * 2);
  unsigned short* enc_att = (unsigned short*)alloc((size_t)B_ * P_ * A_ * 2);
  float* bias_pre    = (float*)alloc(2560 * 4);
  float* bias_g      = (float*)alloc(2048 * 4);
  float* ppart       = (float*)alloc((size_t)ZPRE * B_ * PLD * 4);
  float* gpart       = (float*)alloc((size_t)ZG * B_ * 2048 * 4);
  unsigned short* xh = (unsigned short*)alloc((size_t)B_ * 2560 * 2);
  float* h           = (float*)alloc((size_t)B_ * D_ * 4);
  float* c           = (float*)alloc((size_t)B_ * D_ * 4);
  unsigned short* h_b = (unsigned short*)alloc((size_t)B_ * D_ * 2);
  unsigned short* hnew_b = (unsigned short*)alloc((size_t)T_ * B_ * D_ * 2);

  sort_kernel<<<1, 128, 0, stream>>>(cap_len, caps, order, dec_len, caps_sorted, out_caps, out_declen);
  gather_kernel<<<dim3(392, 128), 256, 0, stream>>>(encoder_out, order, enc_s);
  prep_kernel<<<2048, 256, 0, stream>>>(We, Wd, Wbeta, W_ih, W_hh, Wfc, bd, bbeta, b_ih, b_hh,
                                        We_b, Wpre2_b, Wg_b, Wfc_b, bias_pre, bias_g,
                                        h, c, h_b);

  // enc_att = enc_s @ We^T + be -> bf16 : M=25088, N=512, K=2048
  gemm_bf16<<<dim3(4, 196, 1), 256, 0, stream>>>(
      enc_s, ENC_, We_b, ENC_, be, enc_att, A_, A_, ENC_);

  for (int t = 0; t < T_; t++){
    // ppart[z] = h @ [Wd;Wbeta;W_hh]^T  K-slice (BK=64, 1 iter/slice, 288 blocks)
    gemm_skinny<<<dim3(36, 1, ZPRE), 256, 0, stream>>>(
        h_b, D_, Wpre2_b, D_, ppart, PLD, 512 / ZPRE);

    // attention (sums ppart slices + bias) -> xh = [emb | gate*awe]
    attn_kernel<<<dim3(2, B_), 1024, 0, stream>>>(enc_att, enc_s, ppart, bias_pre, wf, bf,
                                                  emb, caps_sorted, xh, t);

    // gpart[z] = xh @ W_ih^T  K-slice (BK=64, 5 iters/slice)
    gemm_skinny<<<dim3(16, 1, ZG), 256, 0, stream>>>(
        xh, 2560, Wg_b, 2560, gpart, 2048, 2560 / ZG);

    // lstm sums gpart + ppart_hh slices + bias_g
    lstm_kernel<<<(B_ * D_) / 256, 256, 0, stream>>>(gpart, ppart, bias_g, h, c, h_b, hnew_b,
                                                     dec_len, t);
  }

  // preds: (T*B, V) = hnew @ Wfc^T + bfc, masked + scattered to (B,T,V)
  gemm_preds<<<4160, 256, 0, stream>>>(hnew_b, Wfc_b, bfc, out_preds, dec_len);
}

// Round 13
// 3167.466 us; speedup vs baseline: 1.1435x; 1.1435x over previous
//
#include <hip/hip_runtime.h>
#include <cstdint>
#include <cstddef>

#define B_ 128
#define P_ 196
#define ENC_ 2048
#define A_ 512
#define E_ 512
#define D_ 512
#define V_ 10000
#define L_ 52
#define T_ 51
#define ZPRE 8   // split-K slices for pre-GEMM (K=512 -> 64/slice, 1 BK64 iter)
#define ZG 8     // split-K slices for gates GEMM (K=3072 -> 384/slice, 3 BK128 iters)

using short8 = __attribute__((ext_vector_type(8))) short;
using short4v = __attribute__((ext_vector_type(4))) short;
using floatx4 = __attribute__((ext_vector_type(4))) float;

__device__ __forceinline__ float sigf(float x){ return 1.f/(1.f+expf(-x)); }

__device__ __forceinline__ unsigned short f2bf(float f){
  unsigned int u = __float_as_uint(f);
  unsigned int r = (u + 0x7fffu + ((u >> 16) & 1u)) >> 16;
  return (unsigned short)r;
}
__device__ __forceinline__ float bf2f(unsigned short u){
  return __uint_as_float(((unsigned int)u) << 16);
}

// ---------------- sort (stable descending by length) ----------------
__global__ void sort_kernel(const int* __restrict__ cap_len, const int* __restrict__ caps,
                            int* __restrict__ order, int* __restrict__ dec_len,
                            int* __restrict__ caps_sorted,
                            float* __restrict__ out_caps, float* __restrict__ out_declen){
  __shared__ int len_s[B_];
  int i = threadIdx.x;
  len_s[i] = cap_len[i];
  __syncthreads();
  int li = len_s[i];
  int pos = 0;
  for (int j = 0; j < B_; j++){
    int lj = len_s[j];
    pos += (lj > li) || (lj == li && j < i);
  }
  order[pos] = i;
  dec_len[pos] = li - 1;
  out_declen[pos] = (float)(li - 1);
  for (int l = 0; l < L_; l++){
    int v = caps[i * L_ + l];
    caps_sorted[pos * L_ + l] = v;
    out_caps[pos * L_ + l] = (float)v;
  }
}

// ---------------- enc gather + fp32->bf16 ----------------
__global__ void gather_kernel(const float* __restrict__ enc, const int* __restrict__ order,
                              unsigned short* __restrict__ enc_s){
  int b = blockIdx.y;
  int i = (blockIdx.x * 256 + threadIdx.x) * 4;
  const float4 v = *(const float4*)(enc + (size_t)order[b] * (P_ * ENC_) + i);
  short4v r;
  r[0] = (short)f2bf(v.x); r[1] = (short)f2bf(v.y);
  r[2] = (short)f2bf(v.z); r[3] = (short)f2bf(v.w);
  *(short4v*)(enc_s + (size_t)b * (P_ * ENC_) + i) = r;
}

// ---------------- weight conversion/packing + state init ----------------
__global__ void prep_kernel(const float* __restrict__ We, const float* __restrict__ Wd,
                            const float* __restrict__ Wbeta,
                            const float* __restrict__ W_ih, const float* __restrict__ W_hh,
                            const float* __restrict__ Wfc,
                            const float* __restrict__ bd, const float* __restrict__ bbeta,
                            const float* __restrict__ b_ih, const float* __restrict__ b_hh,
                            unsigned short* __restrict__ We_b, unsigned short* __restrict__ Wpre_b,
                            unsigned short* __restrict__ Wg_b, unsigned short* __restrict__ Wfc_b,
                            float* __restrict__ bias_pre, float* __restrict__ bias_g,
                            float* __restrict__ h, float* __restrict__ c,
                            unsigned short* __restrict__ h_b, unsigned short* __restrict__ xh){
  unsigned int idx = blockIdx.x * blockDim.x + threadIdx.x;
  unsigned int stride = gridDim.x * blockDim.x;
  // We_b: 512x2048 direct
  for (unsigned int i = idx; i < 512u * 2048u; i += stride) We_b[i] = f2bf(We[i]);
  // Wpre_b = [Wd(512x512) ; Wbeta(2048x512)] flat concat (K matches)
  for (unsigned int i = idx; i < 2560u * 512u; i += stride)
    Wpre_b[i] = f2bf(i < 512u * 512u ? Wd[i] : Wbeta[i - 512u * 512u]);
  // Wg_b rows: [W_ih row(2560) | W_hh row(512)] -> 2048 x 3072
  for (unsigned int i = idx; i < 2048u * 3072u; i += stride){
    unsigned int j = i / 3072u, k = i - j * 3072u;
    Wg_b[i] = f2bf(k < 2560u ? W_ih[j * 2560u + k] : W_hh[j * 512u + (k - 2560u)]);
  }
  // Wfc_b: 10000x512 direct
  for (unsigned int i = idx; i < 10000u * 512u; i += stride) Wfc_b[i] = f2bf(Wfc[i]);
  // biases
  for (unsigned int i = idx; i < 2560u; i += stride) bias_pre[i] = (i < 512u) ? bd[i] : bbeta[i - 512u];
  for (unsigned int i = idx; i < 2048u; i += stride) bias_g[i] = b_ih[i] + b_hh[i];
  // state init
  for (unsigned int i = idx; i < (unsigned)B_ * D_; i += stride){
    h[i] = 0.f; c[i] = 0.f; h_b[i] = 0;
    unsigned int b = i >> 9, d = i & 511u;
    xh[(size_t)b * 3072 + 2560 + d] = 0;
  }
}

// ---------------- 256-thread GEMM core BK=32, XOR-swizzled LDS ---------------
#define GEMM_CORE(Aptr, LDA, Bptr, LDB, KDIM, NCLAMP)                         \
  int tid = threadIdx.x; int lane = tid & 63; int w = tid >> 6;               \
  const floatx4 vzero = {0.f,0.f,0.f,0.f};                                    \
  floatx4 acc[4][4];                                                          \
  _Pragma("unroll") for (int i_=0;i_<4;i_++)                                  \
  _Pragma("unroll") for (int j_=0;j_<4;j_++) acc[i_][j_]=vzero;               \
  int mbase=(w&1)<<6, nbase=(w>>1)<<6;                                        \
  int fr=lane&15, fk=(lane>>4)<<3;                                            \
  int rsw_ = (fr&3)<<3;                                                       \
  for (int k0=0;k0<(KDIM);k0+=32){                                            \
    _Pragma("unroll") for (int r_=0;r_<2;r_++){                               \
      int chunk=r_*256+tid; int row=chunk>>2, kc=(chunk&3)<<3;                \
      short8 av=*(const short8*)((Aptr)+(size_t)(m0+row)*(LDA)+k0+kc);        \
      int bn=n0+row; if(bn>(NCLAMP)) bn=(NCLAMP);                             \
      short8 bv=*(const short8*)((Bptr)+(size_t)bn*(LDB)+k0+kc);              \
      int sidx = row*32 + (kc ^ ((row&3)<<3));                                \
      *(short8*)&As[sidx]=av; *(short8*)&Bs[sidx]=bv; }                       \
    __syncthreads();                                                          \
    short8 af[4], bfrag[4];                                                   \
    _Pragma("unroll") for (int i_=0;i_<4;i_++){                               \
      af[i_]=*(const short8*)&As[(mbase+i_*16+fr)*32+(fk^rsw_)];              \
      bfrag[i_]=*(const short8*)&Bs[(nbase+i_*16+fr)*32+(fk^rsw_)]; }         \
    _Pragma("unroll") for (int mi_=0;mi_<4;mi_++)                             \
    _Pragma("unroll") for (int ni_=0;ni_<4;ni_++)                             \
      acc[mi_][ni_]=__builtin_amdgcn_mfma_f32_16x16x32_bf16(af[mi_],bfrag[ni_],acc[mi_][ni_],0,0,0); \
    __syncthreads(); }

// ---------------- generic GEMM (epi 0: split-K stores; epi 1: bf16+bias) -----
__launch_bounds__(256)
__global__ void gemm_bf16(const unsigned short* __restrict__ A, int lda,
                          const unsigned short* __restrict__ Bm, int ldb,
                          const float* __restrict__ bias,
                          float* __restrict__ Cf, unsigned short* __restrict__ Cb, int ldc,
                          int N, int ksz, int epi)
{
  __shared__ unsigned short As[128 * 32];
  __shared__ unsigned short Bs[128 * 32];
  int m0 = blockIdx.y * 128, n0 = blockIdx.x * 128;
  int kb = blockIdx.z * ksz;
  const unsigned short* Ap = A + kb;
  const unsigned short* Bp = Bm + kb;
  GEMM_CORE(Ap, lda, Bp, ldb, ksz, N - 1)
  float* Cz = Cf + (size_t)blockIdx.z * ((size_t)B_ * ldc);
#pragma unroll
  for (int mi = 0; mi < 4; mi++)
#pragma unroll
    for (int ni = 0; ni < 4; ni++){
      floatx4 v = acc[mi][ni];
      int col = n0 + nbase + ni * 16 + fr;
      int rb = m0 + mbase + mi * 16 + ((lane >> 4) << 2);
      if (epi == 0){
#pragma unroll
        for (int r = 0; r < 4; r++)
          Cz[(size_t)(rb + r) * ldc + col] = v[r];
      } else {
        float bb = bias[col];
#pragma unroll
        for (int r = 0; r < 4; r++)
          Cb[(size_t)(rb + r) * ldc + col] = f2bf(v[r] + bb);
      }
    }
}

// ---------------- skinny GEMM: M=128, BK=64, XOR-swizzled, split-K stores ----
__launch_bounds__(256)
__global__ void gemm_skinny(const unsigned short* __restrict__ A, int lda,
                            const unsigned short* __restrict__ Bm, int ldb,
                            float* __restrict__ Cf, int ldc, int ksz)
{
  __shared__ unsigned short As[128 * 64];
  __shared__ unsigned short Bs[128 * 64];
  int tid = threadIdx.x; int lane = tid & 63; int w = tid >> 6;
  const floatx4 vzero = {0.f,0.f,0.f,0.f};
  floatx4 acc[4][4];
#pragma unroll
  for (int i_ = 0; i_ < 4; i_++)
#pragma unroll
    for (int j_ = 0; j_ < 4; j_++) acc[i_][j_] = vzero;
  int mbase = (w & 1) << 6, nbase = (w >> 1) << 6;
  int fr = lane & 15, fk = (lane >> 4) << 3;
  int rsw = (fr & 7) << 3;
  int n0 = blockIdx.x * 128;
  int kb = blockIdx.z * ksz;
  const unsigned short* Ap = A + kb;
  const unsigned short* Bp = Bm + kb;
  for (int k0 = 0; k0 < ksz; k0 += 64){
#pragma unroll
    for (int r_ = 0; r_ < 4; r_++){
      int chunk = r_ * 256 + tid;
      int row = chunk >> 3, kc = (chunk & 7) << 3;
      short8 av = *(const short8*)(Ap + (size_t)row * lda + k0 + kc);
      short8 bv = *(const short8*)(Bp + (size_t)(n0 + row) * ldb + k0 + kc);
      int sidx = row * 64 + (kc ^ ((row & 7) << 3));
      *(short8*)&As[sidx] = av;
      *(short8*)&Bs[sidx] = bv;
    }
    __syncthreads();
#pragma unroll
    for (int ks = 0; ks < 2; ks++){
      short8 af[4], bfrag[4];
#pragma unroll
      for (int i_ = 0; i_ < 4; i_++){
        int ra = mbase + i_ * 16 + fr;
        int rb2 = nbase + i_ * 16 + fr;
        af[i_]    = *(const short8*)&As[ra  * 64 + ((ks * 32 + fk) ^ rsw)];
        bfrag[i_] = *(const short8*)&Bs[rb2 * 64 + ((ks * 32 + fk) ^ rsw)];
      }
#pragma unroll
      for (int mi = 0; mi < 4; mi++)
#pragma unroll
        for (int ni = 0; ni < 4; ni++)
          acc[mi][ni] = __builtin_amdgcn_mfma_f32_16x16x32_bf16(af[mi], bfrag[ni], acc[mi][ni], 0, 0, 0);
    }
    __syncthreads();
  }
  float* Cz = Cf + (size_t)blockIdx.z * ((size_t)B_ * ldc);
#pragma unroll
  for (int mi = 0; mi < 4; mi++)
#pragma unroll
    for (int ni = 0; ni < 4; ni++){
      floatx4 v = acc[mi][ni];
      int col = n0 + nbase + ni * 16 + fr;
      int rb = mbase + mi * 16 + ((lane >> 4) << 2);
#pragma unroll
      for (int r = 0; r < 4; r++)
        Cz[(size_t)(rb + r) * ldc + col] = v[r];
    }
}

// ---------------- skinny GEMM BK=128: 3 serial iters for gates ---------------
// LDS 64 KB; swizzle: XOR 8-short group with row&15 (reads land 2-way = free).
__launch_bounds__(256)
__global__ void gemm_skinny128(const unsigned short* __restrict__ A, int lda,
                               const unsigned short* __restrict__ Bm, int ldb,
                               float* __restrict__ Cf, int ldc, int ksz)
{
  __shared__ unsigned short As[128 * 128];
  __shared__ unsigned short Bs[128 * 128];
  int tid = threadIdx.x; int lane = tid & 63; int w = tid >> 6;
  const floatx4 vzero = {0.f,0.f,0.f,0.f};
  floatx4 acc[4][4];
#pragma unroll
  for (int i_ = 0; i_ < 4; i_++)
#pragma unroll
    for (int j_ = 0; j_ < 4; j_++) acc[i_][j_] = vzero;
  int mbase = (w & 1) << 6, nbase = (w >> 1) << 6;
  int fr = lane & 15, fk = (lane >> 4) << 3;
  int rsw = (fr & 15) << 3;
  int n0 = blockIdx.x * 128;
  int kb = blockIdx.z * ksz;
  const unsigned short* Ap = A + kb;
  const unsigned short* Bp = Bm + kb;
  for (int k0 = 0; k0 < ksz; k0 += 128){
#pragma unroll
    for (int r_ = 0; r_ < 8; r_++){
      int chunk = r_ * 256 + tid;
      int row = chunk >> 4, kc = (chunk & 15) << 3;
      short8 av = *(const short8*)(Ap + (size_t)row * lda + k0 + kc);
      short8 bv = *(const short8*)(Bp + (size_t)(n0 + row) * ldb + k0 + kc);
      int sidx = row * 128 + (kc ^ ((row & 15) << 3));
      *(short8*)&As[sidx] = av;
      *(short8*)&Bs[sidx] = bv;
    }
    __syncthreads();
#pragma unroll
    for (int ks = 0; ks < 4; ks++){
      short8 af[4], bfrag[4];
#pragma unroll
      for (int i_ = 0; i_ < 4; i_++){
        int ra = mbase + i_ * 16 + fr;
        int rb2 = nbase + i_ * 16 + fr;
        af[i_]    = *(const short8*)&As[ra  * 128 + ((ks * 32 + fk) ^ rsw)];
        bfrag[i_] = *(const short8*)&Bs[rb2 * 128 + ((ks * 32 + fk) ^ rsw)];
      }
#pragma unroll
      for (int mi = 0; mi < 4; mi++)
#pragma unroll
        for (int ni = 0; ni < 4; ni++)
          acc[mi][ni] = __builtin_amdgcn_mfma_f32_16x16x32_bf16(af[mi], bfrag[ni], acc[mi][ni], 0, 0, 0);
    }
    __syncthreads();
  }
  float* Cz = Cf + (size_t)blockIdx.z * ((size_t)B_ * ldc);
#pragma unroll
  for (int mi = 0; mi < 4; mi++)
#pragma unroll
    for (int ni = 0; ni < 4; ni++){
      floatx4 v = acc[mi][ni];
      int col = n0 + nbase + ni * 16 + fr;
      int rb = mbase + mi * 16 + ((lane >> 4) << 2);
#pragma unroll
      for (int r = 0; r < 4; r++)
        Cz[(size_t)(rb + r) * ldc + col] = v[r];
    }
}

// ---------------- fused attention: scores + softmax + awe + gate -> xh ------
// grid (2, 128) x 1024 threads (round-8 verified structure).
__launch_bounds__(1024)
__global__ void attn_kernel(const unsigned short* __restrict__ enc_att,
                            const unsigned short* __restrict__ enc_s,
                            const float* __restrict__ ppart,      // [ZPRE][128][2560]
                            const float* __restrict__ bias_pre,
                            const float* __restrict__ wf, const float* __restrict__ bfp,
                            const float* __restrict__ emb, const int* __restrict__ caps_sorted,
                            unsigned short* __restrict__ xh,
                            int t){
  __shared__ float sc[P_];
  __shared__ float al[P_];
  __shared__ float red[256];
  __shared__ float part2[8][128][8];   // 32 KB
  int b = blockIdx.y, bx = blockIdx.x, tid = threadIdx.x;

  // ---- phase 1: scores ----
  int wid = tid >> 6, lane = tid & 63;
  float dav[8], wfv[8];
  {
    const float* bp = bias_pre + lane * 8;
    const float* p0 = ppart + (size_t)b * 2560 + lane * 8;
#pragma unroll
    for (int j = 0; j < 8; j++){
      float s = bp[j];
#pragma unroll
      for (int z = 0; z < ZPRE; z++) s += p0[(size_t)z * (B_ * 2560) + j];
      dav[j] = s;
    }
    *(float4*)&wfv[0] = *(const float4*)(wf + lane * 8);
    *(float4*)&wfv[4] = *(const float4*)(wf + lane * 8 + 4);
  }
  float bfv = bfp[0];
  for (int p = wid; p < P_; p += 16){
    short8 e = *(const short8*)(enc_att + ((size_t)b * P_ + p) * A_ + lane * 8);
    float s = 0.f;
#pragma unroll
    for (int j = 0; j < 8; j++){
      float v = bf2f((unsigned short)e[j]) + dav[j];
      s += fmaxf(v, 0.f) * wfv[j];
    }
#pragma unroll
    for (int off = 32; off > 0; off >>= 1) s += __shfl_down(s, off);
    if (lane == 0) sc[p] = s + bfv;
  }
  __syncthreads();

  // ---- phase 2: softmax over 196 ----
  if (tid < 256) red[tid] = (tid < P_) ? sc[tid] : -1e30f;
  __syncthreads();
  for (int s = 128; s > 0; s >>= 1){ if (tid < s) red[tid] = fmaxf(red[tid], red[tid + s]); __syncthreads(); }
  float mx = red[0];
  __syncthreads();
  float ex = 0.f;
  if (tid < 256){ ex = (tid < P_) ? expf(sc[tid] - mx) : 0.f; red[tid] = ex; }
  __syncthreads();
  for (int s = 128; s > 0; s >>= 1){ if (tid < s) red[tid] += red[tid + s]; __syncthreads(); }
  float inv = 1.f / red[0];
  if (tid < P_) al[tid] = ex * inv;
  __syncthreads();

  // ---- phase 3: awe with 8-way p split, 16B loads ----
  int pg = tid >> 7, et = tid & 127;
  int e0 = bx * 1024 + et * 8;
  const unsigned short* encb = enc_s + (size_t)b * (P_ * ENC_) + e0;
  float aa[8];
#pragma unroll
  for (int j = 0; j < 8; j++) aa[j] = 0.f;
  int pbeg = (pg * 196) >> 3, pend = ((pg + 1) * 196) >> 3;
#pragma unroll 5
  for (int p = pbeg; p < pend; p++){
    float a = al[p];
    short8 v = *(const short8*)(encb + (size_t)p * ENC_);
#pragma unroll
    for (int j = 0; j < 8; j++)
      aa[j] += a * bf2f((unsigned short)v[j]);
  }
#pragma unroll
  for (int j = 0; j < 8; j++) part2[pg][et][j] = aa[j];
  __syncthreads();
  if (pg == 0){
    float s[8];
#pragma unroll
    for (int j = 0; j < 8; j++){
      float acc = 0.f;
#pragma unroll
      for (int g = 0; g < 8; g++) acc += part2[g][et][j];
      s[j] = acc;
    }
    const float* bp = bias_pre + 512 + e0;
    const float* p0 = ppart + (size_t)b * 2560 + 512 + e0;
    short8 r;
#pragma unroll
    for (int j = 0; j < 8; j++){
      float g = bp[j];
#pragma unroll
      for (int z = 0; z < ZPRE; z++) g += p0[(size_t)z * (B_ * 2560) + j];
      r[j] = (short)f2bf(sigf(g) * s[j]);
    }
    *(short8*)(xh + (size_t)b * 3072 + 512 + e0) = r;
  }
  // emb gather for this step's token into xh[:512]
  if (bx == 1 && tid < 512){
    int tok = caps_sorted[b * L_ + t];
    xh[(size_t)b * 3072 + tid] = f2bf(emb[(size_t)tok * E_ + tid]);
  }
}

// ---------------- LSTM pointwise: gates = Σz gpart[z] + bias_g ----------------
__global__ void lstm_kernel(const float* __restrict__ gpart,   // [ZG][128][2048]
                            const float* __restrict__ bias_g,
                            float* __restrict__ h, float* __restrict__ c,
                            unsigned short* __restrict__ h_b, unsigned short* __restrict__ xh,
                            unsigned short* __restrict__ hnew_b,
                            const int* __restrict__ dec_len, int t){
  int idx = blockIdx.x * 256 + threadIdx.x;   // 65536 total
  int b = idx >> 9, d = idx & 511;
  const float* gr = gpart + (size_t)b * 2048;
  float i_ = bias_g[d], f_ = bias_g[512 + d], g_ = bias_g[1024 + d], o_ = bias_g[1536 + d];
#pragma unroll
  for (int z = 0; z < ZG; z++){
    const float* gz = gr + (size_t)z * (B_ * 2048);
    i_ += gz[d]; f_ += gz[512 + d]; g_ += gz[1024 + d]; o_ += gz[1536 + d];
  }
  float cn = sigf(f_) * c[idx] + sigf(i_) * tanhf(g_);
  float hn = sigf(o_) * tanhf(cn);
  bool act = t < dec_len[b];
  float hv = act ? hn : h[idx];
  float cv = act ? cn : c[idx];
  h[idx] = hv; c[idx] = cv;
  unsigned short hvb = f2bf(hv);
  h_b[idx] = hvb;
  xh[(size_t)b * 3072 + 2560 + d] = hvb;
  hnew_b[(size_t)t * (B_ * D_) + idx] = f2bf(hn);
}

// ---------------- preds GEMM: XCD-rect partition + LDS-staged stores ---------
__launch_bounds__(256)
__global__ void gemm_preds(const unsigned short* __restrict__ A,    // hnew_b 6528x512
                           const unsigned short* __restrict__ Bm,   // Wfc_b 10000x512
                           const float* __restrict__ bias,
                           float* __restrict__ Cf,
                           const int* __restrict__ dec_len){
  __shared__ __attribute__((aligned(16))) char smem[4 * 64 * 68 * 4];
  unsigned short* As = (unsigned short*)smem;
  unsigned short* Bs = (unsigned short*)(smem + 8192);
  int bid = blockIdx.x;
  int xcd = bid & 7, i = bid >> 3;          // i in [0,520)
  int mchunk = xcd >> 1, nchunk = xcd & 1;
  int mi_ = i % 13, ni_ = i / 13;
  int mt = mchunk * 13 + mi_;
  int nt = nchunk * 40 + ni_;
  if (mt >= 51 || nt >= 79) return;
  int m0 = mt * 128, n0 = nt * 128;
  GEMM_CORE(A, D_, Bm, D_, D_, V_ - 1)
  float* Cs = (float*)smem + (size_t)w * (64 * 68);
#pragma unroll
  for (int mi = 0; mi < 4; mi++)
#pragma unroll
    for (int ni = 0; ni < 4; ni++){
      int lc = ni * 16 + fr;
      int col = n0 + nbase + lc;
      float bb = bias[col < V_ ? col : V_ - 1];
#pragma unroll
      for (int r = 0; r < 4; r++){
        int lr = mi * 16 + ((lane >> 4) << 2) + r;
        Cs[lr * 68 + lc] = acc[mi][ni][r] + bb;
      }
    }
#pragma unroll
  for (int rd = 0; rd < 16; rd++){
    int lr = rd * 4 + (lane >> 4);
    int m = m0 + mbase + lr;
    int tt = m >> 7, b = m & 127;
    int col = n0 + nbase + fr * 4;
    floatx4 v = *(const floatx4*)&Cs[lr * 68 + fr * 4];
    if (tt >= dec_len[b]){ v[0] = 0.f; v[1] = 0.f; v[2] = 0.f; v[3] = 0.f; }
    if (col < V_)
      __builtin_nontemporal_store(v, (floatx4*)(Cf + ((size_t)b * T_ + tt) * V_ + col));
  }
}

extern "C" void kernel_launch(void* const* d_in, const int* in_sizes, int n_in,
                              void* d_out, int out_size, void* d_ws, size_t ws_size,
                              hipStream_t stream) {
  const float* encoder_out = (const float*)d_in[0];
  const int*   caps        = (const int*)d_in[1];
  const int*   cap_len     = (const int*)d_in[2];
  const float* emb         = (const float*)d_in[3];
  const float* We          = (const float*)d_in[4];
  const float* be          = (const float*)d_in[5];
  const float* Wd          = (const float*)d_in[6];
  const float* bd          = (const float*)d_in[7];
  const float* wf          = (const float*)d_in[8];
  const float* bf          = (const float*)d_in[9];
  const float* W_ih        = (const float*)d_in[10];
  const float* b_ih        = (const float*)d_in[11];
  const float* W_hh        = (const float*)d_in[12];
  const float* b_hh        = (const float*)d_in[13];
  const float* Wbeta       = (const float*)d_in[14];
  const float* bbeta       = (const float*)d_in[15];
  const float* Wfc         = (const float*)d_in[16];
  const float* bfc         = (const float*)d_in[17];

  float* out_preds  = (float*)d_out;
  float* out_caps   = out_preds + (size_t)B_ * T_ * V_;
  float* out_declen = out_caps + (size_t)B_ * L_;

  char* w = (char*)d_ws;
  auto alloc = [&](size_t bytes) -> void* {
    void* p = (void*)w;
    w += (bytes + 255) & ~(size_t)255;
    return p;
  };
  int*   order       = (int*)alloc(B_ * 4);
  int*   dec_len     = (int*)alloc(B_ * 4);
  int*   caps_sorted = (int*)alloc((size_t)B_ * L_ * 4);
  unsigned short* enc_s   = (unsigned short*)alloc((size_t)B_ * P_ * ENC_ * 2);
  unsigned short* We_b    = (unsigned short*)alloc((size_t)512 * 2048 * 2);
  unsigned short* Wpre_b  = (unsigned short*)alloc((size_t)2560 * 512 * 2);
  unsigned short* Wg_b    = (unsigned short*)alloc((size_t)2048 * 3072 * 2);
  unsigned short* Wfc_b   = (unsigned short*)alloc((size_t)10000 * 512 * 2);
  unsigned short* enc_att = (unsigned short*)alloc((size_t)B_ * P_ * A_ * 2);
  float* bias_pre    = (float*)alloc(2560 * 4);
  float* bias_g      = (float*)alloc(2048 * 4);
  float* ppart       = (float*)alloc((size_t)ZPRE * B_ * 2560 * 4);
  float* gpart       = (float*)alloc((size_t)ZG * B_ * 2048 * 4);
  unsigned short* xh = (unsigned short*)alloc((size_t)B_ * 3072 * 2);
  float* h           = (float*)alloc((size_t)B_ * D_ * 4);
  float* c           = (float*)alloc((size_t)B_ * D_ * 4);
  unsigned short* h_b = (unsigned short*)alloc((size_t)B_ * D_ * 2);
  unsigned short* hnew_b = (unsigned short*)alloc((size_t)T_ * B_ * D_ * 2);

  sort_kernel<<<1, 128, 0, stream>>>(cap_len, caps, order, dec_len, caps_sorted, out_caps, out_declen);
  gather_kernel<<<dim3(392, 128), 256, 0, stream>>>(encoder_out, order, enc_s);
  prep_kernel<<<2048, 256, 0, stream>>>(We, Wd, Wbeta, W_ih, W_hh, Wfc, bd, bbeta, b_ih, b_hh,
                                        We_b, Wpre_b, Wg_b, Wfc_b, bias_pre, bias_g,
                                        h, c, h_b, xh);

  // enc_att = enc_s @ We^T + be -> bf16 : M=25088, N=512, K=2048
  gemm_bf16<<<dim3(4, 196, 1), 256, 0, stream>>>(
      enc_s, ENC_, We_b, ENC_, be, nullptr, enc_att, A_, A_, ENC_, 1);

  for (int t = 0; t < T_; t++){
    // ppart[z] = h @ [Wd;Wbeta]^T  K-slice (BK=64, 1 iter/slice)
    gemm_skinny<<<dim3(20, 1, ZPRE), 256, 0, stream>>>(
        h_b, D_, Wpre_b, D_, ppart, 2560, 512 / ZPRE);

    // attention (sums ppart slices + bias) -> xh = [emb | gate*awe]
    attn_kernel<<<dim3(2, B_), 1024, 0, stream>>>(enc_att, enc_s, ppart, bias_pre, wf, bf,
                                                  emb, caps_sorted, xh, t);

    // gpart[z] = xh @ [W_ih|W_hh]^T  K-slice (BK=128, 3 iters/slice)
    gemm_skinny128<<<dim3(16, 1, ZG), 256, 0, stream>>>(
        xh, 3072, Wg_b, 3072, gpart, 2048, 3072 / ZG);

    // lstm sums gpart slices + bias_g
    lstm_kernel<<<(B_ * D_) / 256, 256, 0, stream>>>(gpart, bias_g, h, c, h_b, xh, hnew_b,
                                                     dec_len, t);
  }

  // preds: (T*B, V) = hnew @ Wfc^T + bfc, masked + scattered to (B,T,V)
  gemm_preds<<<4160, 256, 0, stream>>>(hnew_b, Wfc_b, bfc, out_preds, dec_len);
}

// Round 14
// 2953.516 us; speedup vs baseline: 1.2264x; 1.0724x over previous
//
#include <hip/hip_runtime.h>
#include <cstdint>
#include <cstddef>

#define B_ 128
#define P_ 196
#define ENC_ 2048
#define A_ 512
#define E_ 512
#define D_ 512
#define V_ 10000
#define L_ 52
#define T_ 51
#define ZPRE 8   // split-K slices for pre-GEMM (K=512 -> 64/slice, 1 BK64 iter)
#define ZG 8     // split-K slices for gates GEMM (K=3072 -> 384/slice, 3 BK128 iters)

using short8 = __attribute__((ext_vector_type(8))) short;
using short4v = __attribute__((ext_vector_type(4))) short;
using floatx4 = __attribute__((ext_vector_type(4))) float;

__device__ __forceinline__ float sigf(float x){ return 1.f/(1.f+expf(-x)); }

__device__ __forceinline__ unsigned short f2bf(float f){
  unsigned int u = __float_as_uint(f);
  unsigned int r = (u + 0x7fffu + ((u >> 16) & 1u)) >> 16;
  return (unsigned short)r;
}
__device__ __forceinline__ float bf2f(unsigned short u){
  return __uint_as_float(((unsigned int)u) << 16);
}

// ---------------- sort (stable descending by length) ----------------
__global__ void sort_kernel(const int* __restrict__ cap_len, const int* __restrict__ caps,
                            int* __restrict__ order, int* __restrict__ dec_len,
                            int* __restrict__ caps_sorted,
                            float* __restrict__ out_caps, float* __restrict__ out_declen){
  __shared__ int len_s[B_];
  int i = threadIdx.x;
  len_s[i] = cap_len[i];
  __syncthreads();
  int li = len_s[i];
  int pos = 0;
  for (int j = 0; j < B_; j++){
    int lj = len_s[j];
    pos += (lj > li) || (lj == li && j < i);
  }
  order[pos] = i;
  dec_len[pos] = li - 1;
  out_declen[pos] = (float)(li - 1);
  for (int l = 0; l < L_; l++){
    int v = caps[i * L_ + l];
    caps_sorted[pos * L_ + l] = v;
    out_caps[pos * L_ + l] = (float)v;
  }
}

// ---------------- enc gather + fp32->bf16 ----------------
__global__ void gather_kernel(const float* __restrict__ enc, const int* __restrict__ order,
                              unsigned short* __restrict__ enc_s){
  int b = blockIdx.y;
  int i = (blockIdx.x * 256 + threadIdx.x) * 4;
  const float4 v = *(const float4*)(enc + (size_t)order[b] * (P_ * ENC_) + i);
  short4v r;
  r[0] = (short)f2bf(v.x); r[1] = (short)f2bf(v.y);
  r[2] = (short)f2bf(v.z); r[3] = (short)f2bf(v.w);
  *(short4v*)(enc_s + (size_t)b * (P_ * ENC_) + i) = r;
}

// ---------------- weight conversion/packing + state init ----------------
__global__ void prep_kernel(const float* __restrict__ We, const float* __restrict__ Wd,
                            const float* __restrict__ Wbeta,
                            const float* __restrict__ W_ih, const float* __restrict__ W_hh,
                            const float* __restrict__ Wfc,
                            const float* __restrict__ bd, const float* __restrict__ bbeta,
                            const float* __restrict__ b_ih, const float* __restrict__ b_hh,
                            unsigned short* __restrict__ We_b, unsigned short* __restrict__ Wpre_b,
                            unsigned short* __restrict__ Wg_b, unsigned short* __restrict__ Wfc_b,
                            float* __restrict__ bias_pre, float* __restrict__ bias_g,
                            float* __restrict__ h, float* __restrict__ c,
                            unsigned short* __restrict__ h_b, unsigned short* __restrict__ xh){
  unsigned int idx = blockIdx.x * blockDim.x + threadIdx.x;
  unsigned int stride = gridDim.x * blockDim.x;
  // We_b: 512x2048 direct
  for (unsigned int i = idx; i < 512u * 2048u; i += stride) We_b[i] = f2bf(We[i]);
  // Wpre_b = [Wd(512x512) ; Wbeta(2048x512)] flat concat (K matches)
  for (unsigned int i = idx; i < 2560u * 512u; i += stride)
    Wpre_b[i] = f2bf(i < 512u * 512u ? Wd[i] : Wbeta[i - 512u * 512u]);
  // Wg_b rows: [W_ih row(2560) | W_hh row(512)] -> 2048 x 3072
  for (unsigned int i = idx; i < 2048u * 3072u; i += stride){
    unsigned int j = i / 3072u, k = i - j * 3072u;
    Wg_b[i] = f2bf(k < 2560u ? W_ih[j * 2560u + k] : W_hh[j * 512u + (k - 2560u)]);
  }
  // Wfc_b: 10000x512 direct
  for (unsigned int i = idx; i < 10000u * 512u; i += stride) Wfc_b[i] = f2bf(Wfc[i]);
  // biases
  for (unsigned int i = idx; i < 2560u; i += stride) bias_pre[i] = (i < 512u) ? bd[i] : bbeta[i - 512u];
  for (unsigned int i = idx; i < 2048u; i += stride) bias_g[i] = b_ih[i] + b_hh[i];
  // state init
  for (unsigned int i = idx; i < (unsigned)B_ * D_; i += stride){
    h[i] = 0.f; c[i] = 0.f; h_b[i] = 0;
    unsigned int b = i >> 9, d = i & 511u;
    xh[(size_t)b * 3072 + 2560 + d] = 0;
  }
}

// ---------------- 256-thread GEMM core BK=32, XOR-swizzled LDS ---------------
#define GEMM_CORE(Aptr, LDA, Bptr, LDB, KDIM, NCLAMP)                         \
  int tid = threadIdx.x; int lane = tid & 63; int w = tid >> 6;               \
  const floatx4 vzero = {0.f,0.f,0.f,0.f};                                    \
  floatx4 acc[4][4];                                                          \
  _Pragma("unroll") for (int i_=0;i_<4;i_++)                                  \
  _Pragma("unroll") for (int j_=0;j_<4;j_++) acc[i_][j_]=vzero;               \
  int mbase=(w&1)<<6, nbase=(w>>1)<<6;                                        \
  int fr=lane&15, fk=(lane>>4)<<3;                                            \
  int rsw_ = (fr&3)<<3;                                                       \
  for (int k0=0;k0<(KDIM);k0+=32){                                            \
    _Pragma("unroll") for (int r_=0;r_<2;r_++){                               \
      int chunk=r_*256+tid; int row=chunk>>2, kc=(chunk&3)<<3;                \
      short8 av=*(const short8*)((Aptr)+(size_t)(m0+row)*(LDA)+k0+kc);        \
      int bn=n0+row; if(bn>(NCLAMP)) bn=(NCLAMP);                             \
      short8 bv=*(const short8*)((Bptr)+(size_t)bn*(LDB)+k0+kc);              \
      int sidx = row*32 + (kc ^ ((row&3)<<3));                                \
      *(short8*)&As[sidx]=av; *(short8*)&Bs[sidx]=bv; }                       \
    __syncthreads();                                                          \
    short8 af[4], bfrag[4];                                                   \
    _Pragma("unroll") for (int i_=0;i_<4;i_++){                               \
      af[i_]=*(const short8*)&As[(mbase+i_*16+fr)*32+(fk^rsw_)];              \
      bfrag[i_]=*(const short8*)&Bs[(nbase+i_*16+fr)*32+(fk^rsw_)]; }         \
    _Pragma("unroll") for (int mi_=0;mi_<4;mi_++)                             \
    _Pragma("unroll") for (int ni_=0;ni_<4;ni_++)                             \
      acc[mi_][ni_]=__builtin_amdgcn_mfma_f32_16x16x32_bf16(af[mi_],bfrag[ni_],acc[mi_][ni_],0,0,0); \
    __syncthreads(); }

// ---------------- generic GEMM (epi 0: split-K stores; epi 1: bf16+bias) -----
__launch_bounds__(256)
__global__ void gemm_bf16(const unsigned short* __restrict__ A, int lda,
                          const unsigned short* __restrict__ Bm, int ldb,
                          const float* __restrict__ bias,
                          float* __restrict__ Cf, unsigned short* __restrict__ Cb, int ldc,
                          int N, int ksz, int epi)
{
  __shared__ unsigned short As[128 * 32];
  __shared__ unsigned short Bs[128 * 32];
  int m0 = blockIdx.y * 128, n0 = blockIdx.x * 128;
  int kb = blockIdx.z * ksz;
  const unsigned short* Ap = A + kb;
  const unsigned short* Bp = Bm + kb;
  GEMM_CORE(Ap, lda, Bp, ldb, ksz, N - 1)
  float* Cz = Cf + (size_t)blockIdx.z * ((size_t)B_ * ldc);
#pragma unroll
  for (int mi = 0; mi < 4; mi++)
#pragma unroll
    for (int ni = 0; ni < 4; ni++){
      floatx4 v = acc[mi][ni];
      int col = n0 + nbase + ni * 16 + fr;
      int rb = m0 + mbase + mi * 16 + ((lane >> 4) << 2);
      if (epi == 0){
#pragma unroll
        for (int r = 0; r < 4; r++)
          Cz[(size_t)(rb + r) * ldc + col] = v[r];
      } else {
        float bb = bias[col];
#pragma unroll
        for (int r = 0; r < 4; r++)
          Cb[(size_t)(rb + r) * ldc + col] = f2bf(v[r] + bb);
      }
    }
}

// ---------------- skinny GEMM: M=128, BK=64, XOR-swizzled, split-K stores ----
__launch_bounds__(256)
__global__ void gemm_skinny(const unsigned short* __restrict__ A, int lda,
                            const unsigned short* __restrict__ Bm, int ldb,
                            float* __restrict__ Cf, int ldc, int ksz)
{
  __shared__ unsigned short As[128 * 64];
  __shared__ unsigned short Bs[128 * 64];
  int tid = threadIdx.x; int lane = tid & 63; int w = tid >> 6;
  const floatx4 vzero = {0.f,0.f,0.f,0.f};
  floatx4 acc[4][4];
#pragma unroll
  for (int i_ = 0; i_ < 4; i_++)
#pragma unroll
    for (int j_ = 0; j_ < 4; j_++) acc[i_][j_] = vzero;
  int mbase = (w & 1) << 6, nbase = (w >> 1) << 6;
  int fr = lane & 15, fk = (lane >> 4) << 3;
  int rsw = (fr & 7) << 3;
  int n0 = blockIdx.x * 128;
  int kb = blockIdx.z * ksz;
  const unsigned short* Ap = A + kb;
  const unsigned short* Bp = Bm + kb;
  for (int k0 = 0; k0 < ksz; k0 += 64){
#pragma unroll
    for (int r_ = 0; r_ < 4; r_++){
      int chunk = r_ * 256 + tid;
      int row = chunk >> 3, kc = (chunk & 7) << 3;
      short8 av = *(const short8*)(Ap + (size_t)row * lda + k0 + kc);
      short8 bv = *(const short8*)(Bp + (size_t)(n0 + row) * ldb + k0 + kc);
      int sidx = row * 64 + (kc ^ ((row & 7) << 3));
      *(short8*)&As[sidx] = av;
      *(short8*)&Bs[sidx] = bv;
    }
    __syncthreads();
#pragma unroll
    for (int ks = 0; ks < 2; ks++){
      short8 af[4], bfrag[4];
#pragma unroll
      for (int i_ = 0; i_ < 4; i_++){
        int ra = mbase + i_ * 16 + fr;
        int rb2 = nbase + i_ * 16 + fr;
        af[i_]    = *(const short8*)&As[ra  * 64 + ((ks * 32 + fk) ^ rsw)];
        bfrag[i_] = *(const short8*)&Bs[rb2 * 64 + ((ks * 32 + fk) ^ rsw)];
      }
#pragma unroll
      for (int mi = 0; mi < 4; mi++)
#pragma unroll
        for (int ni = 0; ni < 4; ni++)
          acc[mi][ni] = __builtin_amdgcn_mfma_f32_16x16x32_bf16(af[mi], bfrag[ni], acc[mi][ni], 0, 0, 0);
    }
    __syncthreads();
  }
  float* Cz = Cf + (size_t)blockIdx.z * ((size_t)B_ * ldc);
#pragma unroll
  for (int mi = 0; mi < 4; mi++)
#pragma unroll
    for (int ni = 0; ni < 4; ni++){
      floatx4 v = acc[mi][ni];
      int col = n0 + nbase + ni * 16 + fr;
      int rb = mbase + mi * 16 + ((lane >> 4) << 2);
#pragma unroll
      for (int r = 0; r < 4; r++)
        Cz[(size_t)(rb + r) * ldc + col] = v[r];
    }
}

// ---------------- skinny GEMM BK=128: 3 serial iters for gates ---------------
__launch_bounds__(256)
__global__ void gemm_skinny128(const unsigned short* __restrict__ A, int lda,
                               const unsigned short* __restrict__ Bm, int ldb,
                               float* __restrict__ Cf, int ldc, int ksz)
{
  __shared__ unsigned short As[128 * 128];
  __shared__ unsigned short Bs[128 * 128];
  int tid = threadIdx.x; int lane = tid & 63; int w = tid >> 6;
  const floatx4 vzero = {0.f,0.f,0.f,0.f};
  floatx4 acc[4][4];
#pragma unroll
  for (int i_ = 0; i_ < 4; i_++)
#pragma unroll
    for (int j_ = 0; j_ < 4; j_++) acc[i_][j_] = vzero;
  int mbase = (w & 1) << 6, nbase = (w >> 1) << 6;
  int fr = lane & 15, fk = (lane >> 4) << 3;
  int rsw = (fr & 15) << 3;
  int n0 = blockIdx.x * 128;
  int kb = blockIdx.z * ksz;
  const unsigned short* Ap = A + kb;
  const unsigned short* Bp = Bm + kb;
  for (int k0 = 0; k0 < ksz; k0 += 128){
#pragma unroll
    for (int r_ = 0; r_ < 8; r_++){
      int chunk = r_ * 256 + tid;
      int row = chunk >> 4, kc = (chunk & 15) << 3;
      short8 av = *(const short8*)(Ap + (size_t)row * lda + k0 + kc);
      short8 bv = *(const short8*)(Bp + (size_t)(n0 + row) * ldb + k0 + kc);
      int sidx = row * 128 + (kc ^ ((row & 15) << 3));
      *(short8*)&As[sidx] = av;
      *(short8*)&Bs[sidx] = bv;
    }
    __syncthreads();
#pragma unroll
    for (int ks = 0; ks < 4; ks++){
      short8 af[4], bfrag[4];
#pragma unroll
      for (int i_ = 0; i_ < 4; i_++){
        int ra = mbase + i_ * 16 + fr;
        int rb2 = nbase + i_ * 16 + fr;
        af[i_]    = *(const short8*)&As[ra  * 128 + ((ks * 32 + fk) ^ rsw)];
        bfrag[i_] = *(const short8*)&Bs[rb2 * 128 + ((ks * 32 + fk) ^ rsw)];
      }
#pragma unroll
      for (int mi = 0; mi < 4; mi++)
#pragma unroll
        for (int ni = 0; ni < 4; ni++)
          acc[mi][ni] = __builtin_amdgcn_mfma_f32_16x16x32_bf16(af[mi], bfrag[ni], acc[mi][ni], 0, 0, 0);
    }
    __syncthreads();
  }
  float* Cz = Cf + (size_t)blockIdx.z * ((size_t)B_ * ldc);
#pragma unroll
  for (int mi = 0; mi < 4; mi++)
#pragma unroll
    for (int ni = 0; ni < 4; ni++){
      floatx4 v = acc[mi][ni];
      int col = n0 + nbase + ni * 16 + fr;
      int rb = mbase + mi * 16 + ((lane >> 4) << 2);
#pragma unroll
      for (int r = 0; r < 4; r++)
        Cz[(size_t)(rb + r) * ldc + col] = v[r];
    }
}

// ---------------- fused attention: scores + softmax + awe + gate -> xh ------
// grid (2, 128) x 1024 threads. EARLY-EXIT for inactive b (t >= dec_len[b]):
// downstream consumers of this b's xh are provably masked (lstm freezes h/c,
// preds zeroes row) so skipping is semantics-preserving.
__launch_bounds__(1024)
__global__ void attn_kernel(const unsigned short* __restrict__ enc_att,
                            const unsigned short* __restrict__ enc_s,
                            const float* __restrict__ ppart,      // [ZPRE][128][2560]
                            const float* __restrict__ bias_pre,
                            const float* __restrict__ wf, const float* __restrict__ bfp,
                            const float* __restrict__ emb, const int* __restrict__ caps_sorted,
                            unsigned short* __restrict__ xh,
                            const int* __restrict__ dec_len, int t){
  __shared__ float sc[P_];
  __shared__ float al[P_];
  __shared__ float red[256];
  __shared__ float part2[8][128][8];   // 32 KB
  int b = blockIdx.y, bx = blockIdx.x, tid = threadIdx.x;
  if (t >= dec_len[b]) return;   // inactive batch: all downstream work masked

  // ---- phase 1: scores ----
  int wid = tid >> 6, lane = tid & 63;
  float dav[8], wfv[8];
  {
    const float* bp = bias_pre + lane * 8;
    const float* p0 = ppart + (size_t)b * 2560 + lane * 8;
#pragma unroll
    for (int j = 0; j < 8; j++){
      float s = bp[j];
#pragma unroll
      for (int z = 0; z < ZPRE; z++) s += p0[(size_t)z * (B_ * 2560) + j];
      dav[j] = s;
    }
    *(float4*)&wfv[0] = *(const float4*)(wf + lane * 8);
    *(float4*)&wfv[4] = *(const float4*)(wf + lane * 8 + 4);
  }
  float bfv = bfp[0];
  for (int p = wid; p < P_; p += 16){
    short8 e = *(const short8*)(enc_att + ((size_t)b * P_ + p) * A_ + lane * 8);
    float s = 0.f;
#pragma unroll
    for (int j = 0; j < 8; j++){
      float v = bf2f((unsigned short)e[j]) + dav[j];
      s += fmaxf(v, 0.f) * wfv[j];
    }
#pragma unroll
    for (int off = 32; off > 0; off >>= 1) s += __shfl_down(s, off);
    if (lane == 0) sc[p] = s + bfv;
  }
  __syncthreads();

  // ---- phase 2: softmax over 196 ----
  if (tid < 256) red[tid] = (tid < P_) ? sc[tid] : -1e30f;
  __syncthreads();
  for (int s = 128; s > 0; s >>= 1){ if (tid < s) red[tid] = fmaxf(red[tid], red[tid + s]); __syncthreads(); }
  float mx = red[0];
  __syncthreads();
  float ex = 0.f;
  if (tid < 256){ ex = (tid < P_) ? expf(sc[tid] - mx) : 0.f; red[tid] = ex; }
  __syncthreads();
  for (int s = 128; s > 0; s >>= 1){ if (tid < s) red[tid] += red[tid + s]; __syncthreads(); }
  float inv = 1.f / red[0];
  if (tid < P_) al[tid] = ex * inv;
  __syncthreads();

  // ---- phase 3: awe with 8-way p split, 16B loads ----
  int pg = tid >> 7, et = tid & 127;
  int e0 = bx * 1024 + et * 8;
  const unsigned short* encb = enc_s + (size_t)b * (P_ * ENC_) + e0;
  float aa[8];
#pragma unroll
  for (int j = 0; j < 8; j++) aa[j] = 0.f;
  int pbeg = (pg * 196) >> 3, pend = ((pg + 1) * 196) >> 3;
#pragma unroll 5
  for (int p = pbeg; p < pend; p++){
    float a = al[p];
    short8 v = *(const short8*)(encb + (size_t)p * ENC_);
#pragma unroll
    for (int j = 0; j < 8; j++)
      aa[j] += a * bf2f((unsigned short)v[j]);
  }
#pragma unroll
  for (int j = 0; j < 8; j++) part2[pg][et][j] = aa[j];
  __syncthreads();
  if (pg == 0){
    float s[8];
#pragma unroll
    for (int j = 0; j < 8; j++){
      float acc = 0.f;
#pragma unroll
      for (int g = 0; g < 8; g++) acc += part2[g][et][j];
      s[j] = acc;
    }
    const float* bp = bias_pre + 512 + e0;
    const float* p0 = ppart + (size_t)b * 2560 + 512 + e0;
    short8 r;
#pragma unroll
    for (int j = 0; j < 8; j++){
      float g = bp[j];
#pragma unroll
      for (int z = 0; z < ZPRE; z++) g += p0[(size_t)z * (B_ * 2560) + j];
      r[j] = (short)f2bf(sigf(g) * s[j]);
    }
    *(short8*)(xh + (size_t)b * 3072 + 512 + e0) = r;
  }
  // emb gather for this step's token into xh[:512]
  if (bx == 1 && tid < 512){
    int tok = caps_sorted[b * L_ + t];
    xh[(size_t)b * 3072 + tid] = f2bf(emb[(size_t)tok * E_ + tid]);
  }
}

// ---------------- LSTM pointwise: gates = Σz gpart[z] + bias_g ----------------
// EARLY-EXIT for inactive b: h/c/h_b/xh keep frozen values by omission;
// stale hnew_b rows are only read by preds rows masked to 0 before store.
__global__ void lstm_kernel(const float* __restrict__ gpart,   // [ZG][128][2048]
                            const float* __restrict__ bias_g,
                            float* __restrict__ h, float* __restrict__ c,
                            unsigned short* __restrict__ h_b, unsigned short* __restrict__ xh,
                            unsigned short* __restrict__ hnew_b,
                            const int* __restrict__ dec_len, int t){
  int idx = blockIdx.x * 256 + threadIdx.x;   // 65536 total
  int b = idx >> 9, d = idx & 511;
  if (t >= dec_len[b]) return;
  const float* gr = gpart + (size_t)b * 2048;
  float i_ = bias_g[d], f_ = bias_g[512 + d], g_ = bias_g[1024 + d], o_ = bias_g[1536 + d];
#pragma unroll
  for (int z = 0; z < ZG; z++){
    const float* gz = gr + (size_t)z * (B_ * 2048);
    i_ += gz[d]; f_ += gz[512 + d]; g_ += gz[1024 + d]; o_ += gz[1536 + d];
  }
  float cn = sigf(f_) * c[idx] + sigf(i_) * tanhf(g_);
  float hn = sigf(o_) * tanhf(cn);
  h[idx] = hn; c[idx] = cn;
  unsigned short hvb = f2bf(hn);
  h_b[idx] = hvb;
  xh[(size_t)b * 3072 + 2560 + d] = hvb;
  hnew_b[(size_t)t * (B_ * D_) + idx] = hvb;
}

// ---------------- preds GEMM: XCD-rect partition + LDS-staged stores ---------
__launch_bounds__(256)
__global__ void gemm_preds(const unsigned short* __restrict__ A,    // hnew_b 6528x512
                           const unsigned short* __restrict__ Bm,   // Wfc_b 10000x512
                           const float* __restrict__ bias,
                           float* __restrict__ Cf,
                           const int* __restrict__ dec_len){
  __shared__ __attribute__((aligned(16))) char smem[4 * 64 * 68 * 4];
  unsigned short* As = (unsigned short*)smem;
  unsigned short* Bs = (unsigned short*)(smem + 8192);
  int bid = blockIdx.x;
  int xcd = bid & 7, i = bid >> 3;          // i in [0,520)
  int mchunk = xcd >> 1, nchunk = xcd & 1;
  int mi_ = i % 13, ni_ = i / 13;
  int mt = mchunk * 13 + mi_;
  int nt = nchunk * 40 + ni_;
  if (mt >= 51 || nt >= 79) return;
  int m0 = mt * 128, n0 = nt * 128;
  GEMM_CORE(A, D_, Bm, D_, D_, V_ - 1)
  float* Cs = (float*)smem + (size_t)w * (64 * 68);
#pragma unroll
  for (int mi = 0; mi < 4; mi++)
#pragma unroll
    for (int ni = 0; ni < 4; ni++){
      int lc = ni * 16 + fr;
      int col = n0 + nbase + lc;
      float bb = bias[col < V_ ? col : V_ - 1];
#pragma unroll
      for (int r = 0; r < 4; r++){
        int lr = mi * 16 + ((lane >> 4) << 2) + r;
        Cs[lr * 68 + lc] = acc[mi][ni][r] + bb;
      }
    }
#pragma unroll
  for (int rd = 0; rd < 16; rd++){
    int lr = rd * 4 + (lane >> 4);
    int m = m0 + mbase + lr;
    int tt = m >> 7, b = m & 127;
    int col = n0 + nbase + fr * 4;
    floatx4 v = *(const floatx4*)&Cs[lr * 68 + fr * 4];
    if (tt >= dec_len[b]){ v[0] = 0.f; v[1] = 0.f; v[2] = 0.f; v[3] = 0.f; }
    if (col < V_)
      __builtin_nontemporal_store(v, (floatx4*)(Cf + ((size_t)b * T_ + tt) * V_ + col));
  }
}

extern "C" void kernel_launch(void* const* d_in, const int* in_sizes, int n_in,
                              void* d_out, int out_size, void* d_ws, size_t ws_size,
                              hipStream_t stream) {
  const float* encoder_out = (const float*)d_in[0];
  const int*   caps        = (const int*)d_in[1];
  const int*   cap_len     = (const int*)d_in[2];
  const float* emb         = (const float*)d_in[3];
  const float* We          = (const float*)d_in[4];
  const float* be          = (const float*)d_in[5];
  const float* Wd          = (const float*)d_in[6];
  const float* bd          = (const float*)d_in[7];
  const float* wf          = (const float*)d_in[8];
  const float* bf          = (const float*)d_in[9];
  const float* W_ih        = (const float*)d_in[10];
  const float* b_ih        = (const float*)d_in[11];
  const float* W_hh        = (const float*)d_in[12];
  const float* b_hh        = (const float*)d_in[13];
  const float* Wbeta       = (const float*)d_in[14];
  const float* bbeta       = (const float*)d_in[15];
  const float* Wfc         = (const float*)d_in[16];
  const float* bfc         = (const float*)d_in[17];

  float* out_preds  = (float*)d_out;
  float* out_caps   = out_preds + (size_t)B_ * T_ * V_;
  float* out_declen = out_caps + (size_t)B_ * L_;

  char* w = (char*)d_ws;
  auto alloc = [&](size_t bytes) -> void* {
    void* p = (void*)w;
    w += (bytes + 255) & ~(size_t)255;
    return p;
  };
  int*   order       = (int*)alloc(B_ * 4);
  int*   dec_len     = (int*)alloc(B_ * 4);
  int*   caps_sorted = (int*)alloc((size_t)B_ * L_ * 4);
  unsigned short* enc_s   = (unsigned short*)alloc((size_t)B_ * P_ * ENC_ * 2);
  unsigned short* We_b    = (unsigned short*)alloc((size_t)512 * 2048 * 2);
  unsigned short* Wpre_b  = (unsigned short*)alloc((size_t)2560 * 512 * 2);
  unsigned short* Wg_b    = (unsigned short*)alloc((size_t)2048 * 3072 * 2);
  unsigned short* Wfc_b   = (unsigned short*)alloc((size_t)10000 * 512 * 2);
  unsigned short* enc_att = (unsigned short*)alloc((size_t)B_ * P_ * A_ * 2);
  float* bias_pre    = (float*)alloc(2560 * 4);
  float* bias_g      = (float*)alloc(2048 * 4);
  float* ppart       = (float*)alloc((size_t)ZPRE * B_ * 2560 * 4);
  float* gpart       = (float*)alloc((size_t)ZG * B_ * 2048 * 4);
  unsigned short* xh = (unsigned short*)alloc((size_t)B_ * 3072 * 2);
  float* h           = (float*)alloc((size_t)B_ * D_ * 4);
  float* c           = (float*)alloc((size_t)B_ * D_ * 4);
  unsigned short* h_b = (unsigned short*)alloc((size_t)B_ * D_ * 2);
  unsigned short* hnew_b = (unsigned short*)alloc((size_t)T_ * B_ * D_ * 2);

  sort_kernel<<<1, 128, 0, stream>>>(cap_len, caps, order, dec_len, caps_sorted, out_caps, out_declen);
  gather_kernel<<<dim3(392, 128), 256, 0, stream>>>(encoder_out, order, enc_s);
  prep_kernel<<<2048, 256, 0, stream>>>(We, Wd, Wbeta, W_ih, W_hh, Wfc, bd, bbeta, b_ih, b_hh,
                                        We_b, Wpre_b, Wg_b, Wfc_b, bias_pre, bias_g,
                                        h, c, h_b, xh);

  // enc_att = enc_s @ We^T + be -> bf16 : M=25088, N=512, K=2048
  gemm_bf16<<<dim3(4, 196, 1), 256, 0, stream>>>(
      enc_s, ENC_, We_b, ENC_, be, nullptr, enc_att, A_, A_, ENC_, 1);

  for (int t = 0; t < T_; t++){
    // ppart[z] = h @ [Wd;Wbeta]^T  K-slice (BK=64, 1 iter/slice)
    gemm_skinny<<<dim3(20, 1, ZPRE), 256, 0, stream>>>(
        h_b, D_, Wpre_b, D_, ppart, 2560, 512 / ZPRE);

    // attention (sums ppart slices + bias) -> xh = [emb | gate*awe]
    attn_kernel<<<dim3(2, B_), 1024, 0, stream>>>(enc_att, enc_s, ppart, bias_pre, wf, bf,
                                                  emb, caps_sorted, xh, dec_len, t);

    // gpart[z] = xh @ [W_ih|W_hh]^T  K-slice (BK=128, 3 iters/slice)
    gemm_skinny128<<<dim3(16, 1, ZG), 256, 0, stream>>>(
        xh, 3072, Wg_b, 3072, gpart, 2048, 3072 / ZG);

    // lstm sums gpart slices + bias_g
    lstm_kernel<<<(B_ * D_) / 256, 256, 0, stream>>>(gpart, bias_g, h, c, h_b, xh, hnew_b,
                                                     dec_len, t);
  }

  // preds: (T*B, V) = hnew @ Wfc^T + bfc, masked + scattered to (B,T,V)
  gemm_preds<<<4160, 256, 0, stream>>>(hnew_b, Wfc_b, bfc, out_preds, dec_len);
}

// Round 15
// 2772.794 us; speedup vs baseline: 1.3063x; 1.0652x over previous
//
#include <hip/hip_runtime.h>
#include <cstdint>
#include <cstddef>

#define B_ 128
#define P_ 196
#define ENC_ 2048
#define A_ 512
#define E_ 512
#define D_ 512
#define V_ 10000
#define L_ 52
#define T_ 51
#define ZPRE 4   // split-K slices for pre-GEMM (K=512 -> 128/slice, 1 BK128 iter)
#define ZG 8     // split-K slices for gates GEMM (K=3072 -> 384/slice, 3 BK128 iters)

using short8 = __attribute__((ext_vector_type(8))) short;
using short4v = __attribute__((ext_vector_type(4))) short;
using floatx4 = __attribute__((ext_vector_type(4))) float;

__device__ __forceinline__ float sigf(float x){ return 1.f/(1.f+expf(-x)); }

__device__ __forceinline__ unsigned short f2bf(float f){
  unsigned int u = __float_as_uint(f);
  unsigned int r = (u + 0x7fffu + ((u >> 16) & 1u)) >> 16;
  return (unsigned short)r;
}
__device__ __forceinline__ float bf2f(unsigned short u){
  return __uint_as_float(((unsigned int)u) << 16);
}

// ---------------- sort (stable descending by length) + nact[t] ----------------
__global__ void sort_kernel(const int* __restrict__ cap_len, const int* __restrict__ caps,
                            int* __restrict__ order, int* __restrict__ dec_len,
                            int* __restrict__ caps_sorted,
                            float* __restrict__ out_caps, float* __restrict__ out_declen,
                            int* __restrict__ nact){
  __shared__ int len_s[B_];
  int i = threadIdx.x;
  len_s[i] = cap_len[i];
  __syncthreads();
  int li = len_s[i];
  int pos = 0;
  for (int j = 0; j < B_; j++){
    int lj = len_s[j];
    pos += (lj > li) || (lj == li && j < i);
  }
  order[pos] = i;
  dec_len[pos] = li - 1;
  out_declen[pos] = (float)(li - 1);
  for (int l = 0; l < L_; l++){
    int v = caps[i * L_ + l];
    caps_sorted[pos * L_ + l] = v;
    out_caps[pos * L_ + l] = (float)v;
  }
  // nact[t] = #batches with dec_len > t
  if (i < T_){
    int cnt = 0;
    for (int j = 0; j < B_; j++) cnt += (len_s[j] - 1) > i;
    nact[i] = cnt;
  }
}

// ---------------- enc gather + fp32->bf16 ----------------
__global__ void gather_kernel(const float* __restrict__ enc, const int* __restrict__ order,
                              unsigned short* __restrict__ enc_s){
  int b = blockIdx.y;
  int i = (blockIdx.x * 256 + threadIdx.x) * 4;
  const float4 v = *(const float4*)(enc + (size_t)order[b] * (P_ * ENC_) + i);
  short4v r;
  r[0] = (short)f2bf(v.x); r[1] = (short)f2bf(v.y);
  r[2] = (short)f2bf(v.z); r[3] = (short)f2bf(v.w);
  *(short4v*)(enc_s + (size_t)b * (P_ * ENC_) + i) = r;
}

// ---------------- weight conversion/packing + state init ----------------
__global__ void prep_kernel(const float* __restrict__ We, const float* __restrict__ Wd,
                            const float* __restrict__ Wbeta,
                            const float* __restrict__ W_ih, const float* __restrict__ W_hh,
                            const float* __restrict__ Wfc,
                            const float* __restrict__ bd, const float* __restrict__ bbeta,
                            const float* __restrict__ b_ih, const float* __restrict__ b_hh,
                            unsigned short* __restrict__ We_b, unsigned short* __restrict__ Wpre_b,
                            unsigned short* __restrict__ Wg_b, unsigned short* __restrict__ Wfc_b,
                            float* __restrict__ bias_pre, float* __restrict__ bias_g,
                            float* __restrict__ h, float* __restrict__ c,
                            unsigned short* __restrict__ h_b, unsigned short* __restrict__ xh){
  unsigned int idx = blockIdx.x * blockDim.x + threadIdx.x;
  unsigned int stride = gridDim.x * blockDim.x;
  // We_b: 512x2048 direct
  for (unsigned int i = idx; i < 512u * 2048u; i += stride) We_b[i] = f2bf(We[i]);
  // Wpre_b = [Wd(512x512) ; Wbeta(2048x512)] flat concat (K matches)
  for (unsigned int i = idx; i < 2560u * 512u; i += stride)
    Wpre_b[i] = f2bf(i < 512u * 512u ? Wd[i] : Wbeta[i - 512u * 512u]);
  // Wg_b rows: [W_ih row(2560) | W_hh row(512)] -> 2048 x 3072
  for (unsigned int i = idx; i < 2048u * 3072u; i += stride){
    unsigned int j = i / 3072u, k = i - j * 3072u;
    Wg_b[i] = f2bf(k < 2560u ? W_ih[j * 2560u + k] : W_hh[j * 512u + (k - 2560u)]);
  }
  // Wfc_b: 10000x512 direct
  for (unsigned int i = idx; i < 10000u * 512u; i += stride) Wfc_b[i] = f2bf(Wfc[i]);
  // biases
  for (unsigned int i = idx; i < 2560u; i += stride) bias_pre[i] = (i < 512u) ? bd[i] : bbeta[i - 512u];
  for (unsigned int i = idx; i < 2048u; i += stride) bias_g[i] = b_ih[i] + b_hh[i];
  // state init
  for (unsigned int i = idx; i < (unsigned)B_ * D_; i += stride){
    h[i] = 0.f; c[i] = 0.f; h_b[i] = 0;
    unsigned int b = i >> 9, d = i & 511u;
    xh[(size_t)b * 3072 + 2560 + d] = 0;
  }
}

// ---------------- 256-thread GEMM core BK=32, XOR-swizzled LDS ---------------
#define GEMM_CORE(Aptr, LDA, Bptr, LDB, KDIM, NCLAMP)                         \
  int tid = threadIdx.x; int lane = tid & 63; int w = tid >> 6;               \
  const floatx4 vzero = {0.f,0.f,0.f,0.f};                                    \
  floatx4 acc[4][4];                                                          \
  _Pragma("unroll") for (int i_=0;i_<4;i_++)                                  \
  _Pragma("unroll") for (int j_=0;j_<4;j_++) acc[i_][j_]=vzero;               \
  int mbase=(w&1)<<6, nbase=(w>>1)<<6;                                        \
  int fr=lane&15, fk=(lane>>4)<<3;                                            \
  int rsw_ = (fr&3)<<3;                                                       \
  for (int k0=0;k0<(KDIM);k0+=32){                                            \
    _Pragma("unroll") for (int r_=0;r_<2;r_++){                               \
      int chunk=r_*256+tid; int row=chunk>>2, kc=(chunk&3)<<3;                \
      short8 av=*(const short8*)((Aptr)+(size_t)(m0+row)*(LDA)+k0+kc);        \
      int bn=n0+row; if(bn>(NCLAMP)) bn=(NCLAMP);                             \
      short8 bv=*(const short8*)((Bptr)+(size_t)bn*(LDB)+k0+kc);              \
      int sidx = row*32 + (kc ^ ((row&3)<<3));                                \
      *(short8*)&As[sidx]=av; *(short8*)&Bs[sidx]=bv; }                       \
    __syncthreads();                                                          \
    short8 af[4], bfrag[4];                                                   \
    _Pragma("unroll") for (int i_=0;i_<4;i_++){                               \
      af[i_]=*(const short8*)&As[(mbase+i_*16+fr)*32+(fk^rsw_)];              \
      bfrag[i_]=*(const short8*)&Bs[(nbase+i_*16+fr)*32+(fk^rsw_)]; }         \
    _Pragma("unroll") for (int mi_=0;mi_<4;mi_++)                             \
    _Pragma("unroll") for (int ni_=0;ni_<4;ni_++)                             \
      acc[mi_][ni_]=__builtin_amdgcn_mfma_f32_16x16x32_bf16(af[mi_],bfrag[ni_],acc[mi_][ni_],0,0,0); \
    __syncthreads(); }

// ---------------- generic GEMM (epi 1: bf16+bias) ----------------
__launch_bounds__(256)
__global__ void gemm_bf16(const unsigned short* __restrict__ A, int lda,
                          const unsigned short* __restrict__ Bm, int ldb,
                          const float* __restrict__ bias,
                          unsigned short* __restrict__ Cb, int ldc,
                          int N, int ksz)
{
  __shared__ unsigned short As[128 * 32];
  __shared__ unsigned short Bs[128 * 32];
  int m0 = blockIdx.y * 128, n0 = blockIdx.x * 128;
  GEMM_CORE(A, lda, Bm, ldb, ksz, N - 1)
#pragma unroll
  for (int mi = 0; mi < 4; mi++)
#pragma unroll
    for (int ni = 0; ni < 4; ni++){
      floatx4 v = acc[mi][ni];
      int col = n0 + nbase + ni * 16 + fr;
      int rb = m0 + mbase + mi * 16 + ((lane >> 4) << 2);
      float bb = bias[col];
#pragma unroll
      for (int r = 0; r < 4; r++)
        Cb[(size_t)(rb + r) * ldc + col] = f2bf(v[r] + bb);
    }
}

// ---------------- skinny GEMM 64x128 tile, BK=128, nact-masked M-half -------
// grid (ntiles, 2, Z). Block my=1 exits when nact[t] <= 64 (rows 64+ dead).
// 4 waves each own 64x32 (acc 4x2). LDS 48 KB XOR-swizzled.
__launch_bounds__(256)
__global__ void gemm_skinny64(const unsigned short* __restrict__ A, int lda,
                              const unsigned short* __restrict__ Bm, int ldb,
                              float* __restrict__ Cf, int ldc, int ksz,
                              const int* __restrict__ nact, int t)
{
  __shared__ unsigned short As[64 * 128];
  __shared__ unsigned short Bs[128 * 128];
  int my = blockIdx.y;
  if (my * 64 >= nact[t]) return;   // dead M-half: consumers skip those b
  int tid = threadIdx.x; int lane = tid & 63; int w = tid >> 6;
  const floatx4 vzero = {0.f,0.f,0.f,0.f};
  floatx4 acc[4][2];
#pragma unroll
  for (int i_ = 0; i_ < 4; i_++){ acc[i_][0] = vzero; acc[i_][1] = vzero; }
  int nbase = w << 5;
  int fr = lane & 15, fk = (lane >> 4) << 3;
  int rsw = (fr & 15) << 3;
  int n0 = blockIdx.x * 128;
  int m0g = my * 64;
  int kb = blockIdx.z * ksz;
  const unsigned short* Ap = A + kb;
  const unsigned short* Bp = Bm + kb;
  for (int k0 = 0; k0 < ksz; k0 += 128){
#pragma unroll
    for (int r_ = 0; r_ < 4; r_++){
      int chunk = r_ * 256 + tid;            // A: 64*16 = 1024 chunks
      int row = chunk >> 4, kc = (chunk & 15) << 3;
      short8 av = *(const short8*)(Ap + (size_t)(m0g + row) * lda + k0 + kc);
      int sidx = row * 128 + (kc ^ ((row & 15) << 3));
      *(short8*)&As[sidx] = av;
    }
#pragma unroll
    for (int r_ = 0; r_ < 8; r_++){
      int chunk = r_ * 256 + tid;            // B: 128*16 = 2048 chunks
      int row = chunk >> 4, kc = (chunk & 15) << 3;
      short8 bv = *(const short8*)(Bp + (size_t)(n0 + row) * ldb + k0 + kc);
      int sidx = row * 128 + (kc ^ ((row & 15) << 3));
      *(short8*)&Bs[sidx] = bv;
    }
    __syncthreads();
#pragma unroll
    for (int ks = 0; ks < 4; ks++){
      short8 af[4], bfr[2];
#pragma unroll
      for (int i_ = 0; i_ < 4; i_++)
        af[i_] = *(const short8*)&As[(i_ * 16 + fr) * 128 + ((ks * 32 + fk) ^ rsw)];
      bfr[0] = *(const short8*)&Bs[(nbase + fr) * 128 + ((ks * 32 + fk) ^ rsw)];
      bfr[1] = *(const short8*)&Bs[(nbase + 16 + fr) * 128 + ((ks * 32 + fk) ^ rsw)];
#pragma unroll
      for (int mi = 0; mi < 4; mi++){
        acc[mi][0] = __builtin_amdgcn_mfma_f32_16x16x32_bf16(af[mi], bfr[0], acc[mi][0], 0, 0, 0);
        acc[mi][1] = __builtin_amdgcn_mfma_f32_16x16x32_bf16(af[mi], bfr[1], acc[mi][1], 0, 0, 0);
      }
    }
    __syncthreads();
  }
  float* Cz = Cf + (size_t)blockIdx.z * ((size_t)B_ * ldc);
#pragma unroll
  for (int mi = 0; mi < 4; mi++)
#pragma unroll
    for (int ni = 0; ni < 2; ni++){
      floatx4 v = acc[mi][ni];
      int col = n0 + nbase + ni * 16 + fr;
      int rb = m0g + mi * 16 + ((lane >> 4) << 2);
#pragma unroll
      for (int r = 0; r < 4; r++)
        Cz[(size_t)(rb + r) * ldc + col] = v[r];
    }
}

// ---------------- fused attention: scores + softmax + awe + gate -> xh ------
// grid (2, 128) x 1024 threads; EARLY-EXIT for inactive b.
__launch_bounds__(1024)
__global__ void attn_kernel(const unsigned short* __restrict__ enc_att,
                            const unsigned short* __restrict__ enc_s,
                            const float* __restrict__ ppart,      // [ZPRE][128][2560]
                            const float* __restrict__ bias_pre,
                            const float* __restrict__ wf, const float* __restrict__ bfp,
                            const float* __restrict__ emb, const int* __restrict__ caps_sorted,
                            unsigned short* __restrict__ xh,
                            const int* __restrict__ dec_len, int t){
  __shared__ float sc[P_];
  __shared__ float al[P_];
  __shared__ float red[256];
  __shared__ float part2[8][128][8];   // 32 KB
  int b = blockIdx.y, bx = blockIdx.x, tid = threadIdx.x;
  if (t >= dec_len[b]) return;   // inactive batch: all downstream work masked

  // ---- phase 1: scores ----
  int wid = tid >> 6, lane = tid & 63;
  float dav[8], wfv[8];
  {
    const float* bp = bias_pre + lane * 8;
    const float* p0 = ppart + (size_t)b * 2560 + lane * 8;
#pragma unroll
    for (int j = 0; j < 8; j++){
      float s = bp[j];
#pragma unroll
      for (int z = 0; z < ZPRE; z++) s += p0[(size_t)z * (B_ * 2560) + j];
      dav[j] = s;
    }
    *(float4*)&wfv[0] = *(const float4*)(wf + lane * 8);
    *(float4*)&wfv[4] = *(const float4*)(wf + lane * 8 + 4);
  }
  float bfv = bfp[0];
  for (int p = wid; p < P_; p += 16){
    short8 e = *(const short8*)(enc_att + ((size_t)b * P_ + p) * A_ + lane * 8);
    float s = 0.f;
#pragma unroll
    for (int j = 0; j < 8; j++){
      float v = bf2f((unsigned short)e[j]) + dav[j];
      s += fmaxf(v, 0.f) * wfv[j];
    }
#pragma unroll
    for (int off = 32; off > 0; off >>= 1) s += __shfl_down(s, off);
    if (lane == 0) sc[p] = s + bfv;
  }
  __syncthreads();

  // ---- phase 2: softmax over 196 ----
  if (tid < 256) red[tid] = (tid < P_) ? sc[tid] : -1e30f;
  __syncthreads();
  for (int s = 128; s > 0; s >>= 1){ if (tid < s) red[tid] = fmaxf(red[tid], red[tid + s]); __syncthreads(); }
  float mx = red[0];
  __syncthreads();
  float ex = 0.f;
  if (tid < 256){ ex = (tid < P_) ? expf(sc[tid] - mx) : 0.f; red[tid] = ex; }
  __syncthreads();
  for (int s = 128; s > 0; s >>= 1){ if (tid < s) red[tid] += red[tid + s]; __syncthreads(); }
  float inv = 1.f / red[0];
  if (tid < P_) al[tid] = ex * inv;
  __syncthreads();

  // ---- phase 3: awe with 8-way p split, 16B loads ----
  int pg = tid >> 7, et = tid & 127;
  int e0 = bx * 1024 + et * 8;
  const unsigned short* encb = enc_s + (size_t)b * (P_ * ENC_) + e0;
  float aa[8];
#pragma unroll
  for (int j = 0; j < 8; j++) aa[j] = 0.f;
  int pbeg = (pg * 196) >> 3, pend = ((pg + 1) * 196) >> 3;
#pragma unroll 5
  for (int p = pbeg; p < pend; p++){
    float a = al[p];
    short8 v = *(const short8*)(encb + (size_t)p * ENC_);
#pragma unroll
    for (int j = 0; j < 8; j++)
      aa[j] += a * bf2f((unsigned short)v[j]);
  }
#pragma unroll
  for (int j = 0; j < 8; j++) part2[pg][et][j] = aa[j];
  __syncthreads();
  if (pg == 0){
    float s[8];
#pragma unroll
    for (int j = 0; j < 8; j++){
      float acc = 0.f;
#pragma unroll
      for (int g = 0; g < 8; g++) acc += part2[g][et][j];
      s[j] = acc;
    }
    const float* bp = bias_pre + 512 + e0;
    const float* p0 = ppart + (size_t)b * 2560 + 512 + e0;
    short8 r;
#pragma unroll
    for (int j = 0; j < 8; j++){
      float g = bp[j];
#pragma unroll
      for (int z = 0; z < ZPRE; z++) g += p0[(size_t)z * (B_ * 2560) + j];
      r[j] = (short)f2bf(sigf(g) * s[j]);
    }
    *(short8*)(xh + (size_t)b * 3072 + 512 + e0) = r;
  }
  // emb gather for this step's token into xh[:512]
  if (bx == 1 && tid < 512){
    int tok = caps_sorted[b * L_ + t];
    xh[(size_t)b * 3072 + tid] = f2bf(emb[(size_t)tok * E_ + tid]);
  }
}

// ---------------- LSTM pointwise: gates = Σz gpart[z] + bias_g ----------------
__global__ void lstm_kernel(const float* __restrict__ gpart,   // [ZG][128][2048]
                            const float* __restrict__ bias_g,
                            float* __restrict__ h, float* __restrict__ c,
                            unsigned short* __restrict__ h_b, unsigned short* __restrict__ xh,
                            unsigned short* __restrict__ hnew_b,
                            const int* __restrict__ dec_len, int t){
  int idx = blockIdx.x * 256 + threadIdx.x;   // 65536 total
  int b = idx >> 9, d = idx & 511;
  if (t >= dec_len[b]) return;
  const float* gr = gpart + (size_t)b * 2048;
  float i_ = bias_g[d], f_ = bias_g[512 + d], g_ = bias_g[1024 + d], o_ = bias_g[1536 + d];
#pragma unroll
  for (int z = 0; z < ZG; z++){
    const float* gz = gr + (size_t)z * (B_ * 2048);
    i_ += gz[d]; f_ += gz[512 + d]; g_ += gz[1024 + d]; o_ += gz[1536 + d];
  }
  float cn = sigf(f_) * c[idx] + sigf(i_) * tanhf(g_);
  float hn = sigf(o_) * tanhf(cn);
  h[idx] = hn; c[idx] = cn;
  unsigned short hvb = f2bf(hn);
  h_b[idx] = hvb;
  xh[(size_t)b * 3072 + 2560 + d] = hvb;
  hnew_b[(size_t)t * (B_ * D_) + idx] = hvb;
}

// ---------------- preds GEMM: XCD-rect partition + LDS-staged stores ---------
__launch_bounds__(256)
__global__ void gemm_preds(const unsigned short* __restrict__ A,    // hnew_b 6528x512
                           const unsigned short* __restrict__ Bm,   // Wfc_b 10000x512
                           const float* __restrict__ bias,
                           float* __restrict__ Cf,
                           const int* __restrict__ dec_len){
  __shared__ __attribute__((aligned(16))) char smem[4 * 64 * 68 * 4];
  unsigned short* As = (unsigned short*)smem;
  unsigned short* Bs = (unsigned short*)(smem + 8192);
  int bid = blockIdx.x;
  int xcd = bid & 7, i = bid >> 3;          // i in [0,520)
  int mchunk = xcd >> 1, nchunk = xcd & 1;
  int mi_ = i % 13, ni_ = i / 13;
  int mt = mchunk * 13 + mi_;
  int nt = nchunk * 40 + ni_;
  if (mt >= 51 || nt >= 79) return;
  int m0 = mt * 128, n0 = nt * 128;
  GEMM_CORE(A, D_, Bm, D_, D_, V_ - 1)
  float* Cs = (float*)smem + (size_t)w * (64 * 68);
#pragma unroll
  for (int mi = 0; mi < 4; mi++)
#pragma unroll
    for (int ni = 0; ni < 4; ni++){
      int lc = ni * 16 + fr;
      int col = n0 + nbase + lc;
      float bb = bias[col < V_ ? col : V_ - 1];
#pragma unroll
      for (int r = 0; r < 4; r++){
        int lr = mi * 16 + ((lane >> 4) << 2) + r;
        Cs[lr * 68 + lc] = acc[mi][ni][r] + bb;
      }
    }
#pragma unroll
  for (int rd = 0; rd < 16; rd++){
    int lr = rd * 4 + (lane >> 4);
    int m = m0 + mbase + lr;
    int tt = m >> 7, b = m & 127;
    int col = n0 + nbase + fr * 4;
    floatx4 v = *(const floatx4*)&Cs[lr * 68 + fr * 4];
    if (tt >= dec_len[b]){ v[0] = 0.f; v[1] = 0.f; v[2] = 0.f; v[3] = 0.f; }
    if (col < V_)
      __builtin_nontemporal_store(v, (floatx4*)(Cf + ((size_t)b * T_ + tt) * V_ + col));
  }
}

extern "C" void kernel_launch(void* const* d_in, const int* in_sizes, int n_in,
                              void* d_out, int out_size, void* d_ws, size_t ws_size,
                              hipStream_t stream) {
  const float* encoder_out = (const float*)d_in[0];
  const int*   caps        = (const int*)d_in[1];
  const int*   cap_len     = (const int*)d_in[2];
  const float* emb         = (const float*)d_in[3];
  const float* We          = (const float*)d_in[4];
  const float* be          = (const float*)d_in[5];
  const float* Wd          = (const float*)d_in[6];
  const float* bd          = (const float*)d_in[7];
  const float* wf          = (const float*)d_in[8];
  const float* bf          = (const float*)d_in[9];
  const float* W_ih        = (const float*)d_in[10];
  const float* b_ih        = (const float*)d_in[11];
  const float* W_hh        = (const float*)d_in[12];
  const float* b_hh        = (const float*)d_in[13];
  const float* Wbeta       = (const float*)d_in[14];
  const float* bbeta       = (const float*)d_in[15];
  const float* Wfc         = (const float*)d_in[16];
  const float* bfc         = (const float*)d_in[17];

  float* out_preds  = (float*)d_out;
  float* out_caps   = out_preds + (size_t)B_ * T_ * V_;
  float* out_declen = out_caps + (size_t)B_ * L_;

  char* w = (char*)d_ws;
  auto alloc = [&](size_t bytes) -> void* {
    void* p = (void*)w;
    w += (bytes + 255) & ~(size_t)255;
    return p;
  };
  int*   order       = (int*)alloc(B_ * 4);
  int*   dec_len     = (int*)alloc(B_ * 4);
  int*   nact        = (int*)alloc(64 * 4);
  int*   caps_sorted = (int*)alloc((size_t)B_ * L_ * 4);
  unsigned short* enc_s   = (unsigned short*)alloc((size_t)B_ * P_ * ENC_ * 2);
  unsigned short* We_b    = (unsigned short*)alloc((size_t)512 * 2048 * 2);
  unsigned short* Wpre_b  = (unsigned short*)alloc((size_t)2560 * 512 * 2);
  unsigned short* Wg_b    = (unsigned short*)alloc((size_t)2048 * 3072 * 2);
  unsigned short* Wfc_b   = (unsigned short*)alloc((size_t)10000 * 512 * 2);
  unsigned short* enc_att = (unsigned short*)alloc((size_t)B_ * P_ * A_ * 2);
  float* bias_pre    = (float*)alloc(2560 * 4);
  float* bias_g      = (float*)alloc(2048 * 4);
  float* ppart       = (float*)alloc((size_t)ZPRE * B_ * 2560 * 4);
  float* gpart       = (float*)alloc((size_t)ZG * B_ * 2048 * 4);
  unsigned short* xh = (unsigned short*)alloc((size_t)B_ * 3072 * 2);
  float* h           = (float*)alloc((size_t)B_ * D_ * 4);
  float* c           = (float*)alloc((size_t)B_ * D_ * 4);
  unsigned short* h_b = (unsigned short*)alloc((size_t)B_ * D_ * 2);
  unsigned short* hnew_b = (unsigned short*)alloc((size_t)T_ * B_ * D_ * 2);

  sort_kernel<<<1, 128, 0, stream>>>(cap_len, caps, order, dec_len, caps_sorted,
                                     out_caps, out_declen, nact);
  gather_kernel<<<dim3(392, 128), 256, 0, stream>>>(encoder_out, order, enc_s);
  prep_kernel<<<2048, 256, 0, stream>>>(We, Wd, Wbeta, W_ih, W_hh, Wfc, bd, bbeta, b_ih, b_hh,
                                        We_b, Wpre_b, Wg_b, Wfc_b, bias_pre, bias_g,
                                        h, c, h_b, xh);

  // enc_att = enc_s @ We^T + be -> bf16 : M=25088, N=512, K=2048
  gemm_bf16<<<dim3(4, 196, 1), 256, 0, stream>>>(
      enc_s, ENC_, We_b, ENC_, be, enc_att, A_, A_, ENC_);

  for (int t = 0; t < T_; t++){
    // ppart[z] = h @ [Wd;Wbeta]^T  (64-row tiles, BK=128, 1 iter, nact-masked)
    gemm_skinny64<<<dim3(20, 2, ZPRE), 256, 0, stream>>>(
        h_b, D_, Wpre_b, D_, ppart, 2560, 512 / ZPRE, nact, t);

    // attention (sums ppart slices + bias) -> xh = [emb | gate*awe]
    attn_kernel<<<dim3(2, B_), 1024, 0, stream>>>(enc_att, enc_s, ppart, bias_pre, wf, bf,
                                                  emb, caps_sorted, xh, dec_len, t);

    // gpart[z] = xh @ [W_ih|W_hh]^T  (64-row tiles, BK=128, 3 iters, nact-masked)
    gemm_skinny64<<<dim3(16, 2, ZG), 256, 0, stream>>>(
        xh, 3072, Wg_b, 3072, gpart, 2048, 3072 / ZG, nact, t);

    // lstm sums gpart slices + bias_g
    lstm_kernel<<<(B_ * D_) / 256, 256, 0, stream>>>(gpart, bias_g, h, c, h_b, xh, hnew_b,
                                                     dec_len, t);
  }

  // preds: (T*B, V) = hnew @ Wfc^T + bfc, masked + scattered to (B,T,V)
  gemm_preds<<<4160, 256, 0, stream>>>(hnew_b, Wfc_b, bfc, out_preds, dec_len);
}

// Round 16
// 2742.258 us; speedup vs baseline: 1.3208x; 1.0111x over previous
//
#include <hip/hip_runtime.h>
#include <cstdint>
#include <cstddef>

#define B_ 128
#define P_ 196
#define ENC_ 2048
#define A_ 512
#define E_ 512
#define D_ 512
#define V_ 10000
#define L_ 52
#define T_ 51
#define ZPRE 4   // split-K slices for pre-GEMM (K=512 -> 128/slice, 1 BK128 iter)
#define ZG 8     // split-K slices for gates GEMM (K=3072 -> 384/slice, 3 BK128 iters)

using short8 = __attribute__((ext_vector_type(8))) short;
using short4v = __attribute__((ext_vector_type(4))) short;
using floatx4 = __attribute__((ext_vector_type(4))) float;

__device__ __forceinline__ float sigf(float x){ return 1.f/(1.f+expf(-x)); }

__device__ __forceinline__ unsigned short f2bf(float f){
  unsigned int u = __float_as_uint(f);
  unsigned int r = (u + 0x7fffu + ((u >> 16) & 1u)) >> 16;
  return (unsigned short)r;
}
__device__ __forceinline__ float bf2f(unsigned short u){
  return __uint_as_float(((unsigned int)u) << 16);
}

// ---------------- sort (stable descending by length) + nact[t] ----------------
__global__ void sort_kernel(const int* __restrict__ cap_len, const int* __restrict__ caps,
                            int* __restrict__ order, int* __restrict__ dec_len,
                            int* __restrict__ caps_sorted,
                            float* __restrict__ out_caps, float* __restrict__ out_declen,
                            int* __restrict__ nact){
  __shared__ int len_s[B_];
  int i = threadIdx.x;
  len_s[i] = cap_len[i];
  __syncthreads();
  int li = len_s[i];
  int pos = 0;
  for (int j = 0; j < B_; j++){
    int lj = len_s[j];
    pos += (lj > li) || (lj == li && j < i);
  }
  order[pos] = i;
  dec_len[pos] = li - 1;
  out_declen[pos] = (float)(li - 1);
  for (int l = 0; l < L_; l++){
    int v = caps[i * L_ + l];
    caps_sorted[pos * L_ + l] = v;
    out_caps[pos * L_ + l] = (float)v;
  }
  // nact[t] = #batches with dec_len > t
  if (i < T_){
    int cnt = 0;
    for (int j = 0; j < B_; j++) cnt += (len_s[j] - 1) > i;
    nact[i] = cnt;
  }
}

// ---------------- enc gather + fp32->bf16 ----------------
__global__ void gather_kernel(const float* __restrict__ enc, const int* __restrict__ order,
                              unsigned short* __restrict__ enc_s){
  int b = blockIdx.y;
  int i = (blockIdx.x * 256 + threadIdx.x) * 4;
  const float4 v = *(const float4*)(enc + (size_t)order[b] * (P_ * ENC_) + i);
  short4v r;
  r[0] = (short)f2bf(v.x); r[1] = (short)f2bf(v.y);
  r[2] = (short)f2bf(v.z); r[3] = (short)f2bf(v.w);
  *(short4v*)(enc_s + (size_t)b * (P_ * ENC_) + i) = r;
}

// ---------------- weight conversion/packing + state init ----------------
__global__ void prep_kernel(const float* __restrict__ We, const float* __restrict__ Wd,
                            const float* __restrict__ Wbeta,
                            const float* __restrict__ W_ih, const float* __restrict__ W_hh,
                            const float* __restrict__ Wfc,
                            const float* __restrict__ bd, const float* __restrict__ bbeta,
                            const float* __restrict__ b_ih, const float* __restrict__ b_hh,
                            unsigned short* __restrict__ We_b, unsigned short* __restrict__ Wpre_b,
                            unsigned short* __restrict__ Wg_b, unsigned short* __restrict__ Wfc_b,
                            float* __restrict__ bias_pre, float* __restrict__ bias_g,
                            float* __restrict__ h, float* __restrict__ c,
                            unsigned short* __restrict__ h_b, unsigned short* __restrict__ xh){
  unsigned int idx = blockIdx.x * blockDim.x + threadIdx.x;
  unsigned int stride = gridDim.x * blockDim.x;
  // We_b: 512x2048 direct
  for (unsigned int i = idx; i < 512u * 2048u; i += stride) We_b[i] = f2bf(We[i]);
  // Wpre_b = [Wd(512x512) ; Wbeta(2048x512)] flat concat (K matches)
  for (unsigned int i = idx; i < 2560u * 512u; i += stride)
    Wpre_b[i] = f2bf(i < 512u * 512u ? Wd[i] : Wbeta[i - 512u * 512u]);
  // Wg_b rows: [W_ih row(2560) | W_hh row(512)] -> 2048 x 3072
  for (unsigned int i = idx; i < 2048u * 3072u; i += stride){
    unsigned int j = i / 3072u, k = i - j * 3072u;
    Wg_b[i] = f2bf(k < 2560u ? W_ih[j * 2560u + k] : W_hh[j * 512u + (k - 2560u)]);
  }
  // Wfc_b: 10000x512 direct
  for (unsigned int i = idx; i < 10000u * 512u; i += stride) Wfc_b[i] = f2bf(Wfc[i]);
  // biases
  for (unsigned int i = idx; i < 2560u; i += stride) bias_pre[i] = (i < 512u) ? bd[i] : bbeta[i - 512u];
  for (unsigned int i = idx; i < 2048u; i += stride) bias_g[i] = b_ih[i] + b_hh[i];
  // state init
  for (unsigned int i = idx; i < (unsigned)B_ * D_; i += stride){
    h[i] = 0.f; c[i] = 0.f; h_b[i] = 0;
    unsigned int b = i >> 9, d = i & 511u;
    xh[(size_t)b * 3072 + 2560 + d] = 0;
  }
}

// ---------------- enc_att GEMM: 128x128 tile, BK=64, XOR-swizzled ----------
// M=25088, N=512, K=2048 -> 32 serial iters (was 64 at BK=32).
__launch_bounds__(256)
__global__ void gemm_encatt(const unsigned short* __restrict__ A,
                            const unsigned short* __restrict__ Bm,
                            const float* __restrict__ bias,
                            unsigned short* __restrict__ Cb){
  __shared__ unsigned short As[128 * 64];
  __shared__ unsigned short Bs[128 * 64];
  int tid = threadIdx.x; int lane = tid & 63; int w = tid >> 6;
  const floatx4 vzero = {0.f,0.f,0.f,0.f};
  floatx4 acc[4][4];
#pragma unroll
  for (int i_ = 0; i_ < 4; i_++)
#pragma unroll
    for (int j_ = 0; j_ < 4; j_++) acc[i_][j_] = vzero;
  int mbase = (w & 1) << 6, nbase = (w >> 1) << 6;
  int fr = lane & 15, fk = (lane >> 4) << 3;
  int rsw = (fr & 7) << 3;
  int m0 = blockIdx.y * 128, n0 = blockIdx.x * 128;
  for (int k0 = 0; k0 < ENC_; k0 += 64){
#pragma unroll
    for (int r_ = 0; r_ < 4; r_++){
      int chunk = r_ * 256 + tid;
      int row = chunk >> 3, kc = (chunk & 7) << 3;
      short8 av = *(const short8*)(A + (size_t)(m0 + row) * ENC_ + k0 + kc);
      short8 bv = *(const short8*)(Bm + (size_t)(n0 + row) * ENC_ + k0 + kc);
      int sidx = row * 64 + (kc ^ ((row & 7) << 3));
      *(short8*)&As[sidx] = av;
      *(short8*)&Bs[sidx] = bv;
    }
    __syncthreads();
#pragma unroll
    for (int ks = 0; ks < 2; ks++){
      short8 af[4], bfrag[4];
#pragma unroll
      for (int i_ = 0; i_ < 4; i_++){
        af[i_]    = *(const short8*)&As[(mbase + i_ * 16 + fr) * 64 + ((ks * 32 + fk) ^ rsw)];
        bfrag[i_] = *(const short8*)&Bs[(nbase + i_ * 16 + fr) * 64 + ((ks * 32 + fk) ^ rsw)];
      }
#pragma unroll
      for (int mi = 0; mi < 4; mi++)
#pragma unroll
        for (int ni = 0; ni < 4; ni++)
          acc[mi][ni] = __builtin_amdgcn_mfma_f32_16x16x32_bf16(af[mi], bfrag[ni], acc[mi][ni], 0, 0, 0);
    }
    __syncthreads();
  }
#pragma unroll
  for (int mi = 0; mi < 4; mi++)
#pragma unroll
    for (int ni = 0; ni < 4; ni++){
      floatx4 v = acc[mi][ni];
      int col = n0 + nbase + ni * 16 + fr;
      int rb = m0 + mbase + mi * 16 + ((lane >> 4) << 2);
      float bb = bias[col];
#pragma unroll
      for (int r = 0; r < 4; r++)
        Cb[(size_t)(rb + r) * A_ + col] = f2bf(v[r] + bb);
    }
}

// ---------------- skinny GEMM 64x128 tile, BK=128, nact-masked M-half -------
__launch_bounds__(256)
__global__ void gemm_skinny64(const unsigned short* __restrict__ A, int lda,
                              const unsigned short* __restrict__ Bm, int ldb,
                              float* __restrict__ Cf, int ldc, int ksz,
                              const int* __restrict__ nact, int t)
{
  __shared__ unsigned short As[64 * 128];
  __shared__ unsigned short Bs[128 * 128];
  int my = blockIdx.y;
  if (my * 64 >= nact[t]) return;   // dead M-half: consumers skip those b
  int tid = threadIdx.x; int lane = tid & 63; int w = tid >> 6;
  const floatx4 vzero = {0.f,0.f,0.f,0.f};
  floatx4 acc[4][2];
#pragma unroll
  for (int i_ = 0; i_ < 4; i_++){ acc[i_][0] = vzero; acc[i_][1] = vzero; }
  int nbase = w << 5;
  int fr = lane & 15, fk = (lane >> 4) << 3;
  int rsw = (fr & 15) << 3;
  int n0 = blockIdx.x * 128;
  int m0g = my * 64;
  int kb = blockIdx.z * ksz;
  const unsigned short* Ap = A + kb;
  const unsigned short* Bp = Bm + kb;
  for (int k0 = 0; k0 < ksz; k0 += 128){
#pragma unroll
    for (int r_ = 0; r_ < 4; r_++){
      int chunk = r_ * 256 + tid;            // A: 64*16 = 1024 chunks
      int row = chunk >> 4, kc = (chunk & 15) << 3;
      short8 av = *(const short8*)(Ap + (size_t)(m0g + row) * lda + k0 + kc);
      int sidx = row * 128 + (kc ^ ((row & 15) << 3));
      *(short8*)&As[sidx] = av;
    }
#pragma unroll
    for (int r_ = 0; r_ < 8; r_++){
      int chunk = r_ * 256 + tid;            // B: 128*16 = 2048 chunks
      int row = chunk >> 4, kc = (chunk & 15) << 3;
      short8 bv = *(const short8*)(Bp + (size_t)(n0 + row) * ldb + k0 + kc);
      int sidx = row * 128 + (kc ^ ((row & 15) << 3));
      *(short8*)&Bs[sidx] = bv;
    }
    __syncthreads();
#pragma unroll
    for (int ks = 0; ks < 4; ks++){
      short8 af[4], bfr[2];
#pragma unroll
      for (int i_ = 0; i_ < 4; i_++)
        af[i_] = *(const short8*)&As[(i_ * 16 + fr) * 128 + ((ks * 32 + fk) ^ rsw)];
      bfr[0] = *(const short8*)&Bs[(nbase + fr) * 128 + ((ks * 32 + fk) ^ rsw)];
      bfr[1] = *(const short8*)&Bs[(nbase + 16 + fr) * 128 + ((ks * 32 + fk) ^ rsw)];
#pragma unroll
      for (int mi = 0; mi < 4; mi++){
        acc[mi][0] = __builtin_amdgcn_mfma_f32_16x16x32_bf16(af[mi], bfr[0], acc[mi][0], 0, 0, 0);
        acc[mi][1] = __builtin_amdgcn_mfma_f32_16x16x32_bf16(af[mi], bfr[1], acc[mi][1], 0, 0, 0);
      }
    }
    __syncthreads();
  }
  float* Cz = Cf + (size_t)blockIdx.z * ((size_t)B_ * ldc);
#pragma unroll
  for (int mi = 0; mi < 4; mi++)
#pragma unroll
    for (int ni = 0; ni < 2; ni++){
      floatx4 v = acc[mi][ni];
      int col = n0 + nbase + ni * 16 + fr;
      int rb = m0g + mi * 16 + ((lane >> 4) << 2);
#pragma unroll
      for (int r = 0; r < 4; r++)
        Cz[(size_t)(rb + r) * ldc + col] = v[r];
    }
}

// ---------------- fused attention: scores + softmax + awe + gate -> xh ------
// grid (2, 128) x 1024 threads; EARLY-EXIT for inactive b.
__launch_bounds__(1024)
__global__ void attn_kernel(const unsigned short* __restrict__ enc_att,
                            const unsigned short* __restrict__ enc_s,
                            const float* __restrict__ ppart,      // [ZPRE][128][2560]
                            const float* __restrict__ bias_pre,
                            const float* __restrict__ wf, const float* __restrict__ bfp,
                            const float* __restrict__ emb, const int* __restrict__ caps_sorted,
                            unsigned short* __restrict__ xh,
                            const int* __restrict__ dec_len, int t){
  __shared__ float sc[P_];
  __shared__ float al[P_];
  __shared__ float red[256];
  __shared__ float part2[8][128][8];   // 32 KB
  int b = blockIdx.y, bx = blockIdx.x, tid = threadIdx.x;
  if (t >= dec_len[b]) return;   // inactive batch: all downstream work masked

  // ---- phase 1: scores ----
  int wid = tid >> 6, lane = tid & 63;
  float dav[8], wfv[8];
  {
    const float* bp = bias_pre + lane * 8;
    const float* p0 = ppart + (size_t)b * 2560 + lane * 8;
#pragma unroll
    for (int j = 0; j < 8; j++){
      float s = bp[j];
#pragma unroll
      for (int z = 0; z < ZPRE; z++) s += p0[(size_t)z * (B_ * 2560) + j];
      dav[j] = s;
    }
    *(float4*)&wfv[0] = *(const float4*)(wf + lane * 8);
    *(float4*)&wfv[4] = *(const float4*)(wf + lane * 8 + 4);
  }
  float bfv = bfp[0];
  for (int p = wid; p < P_; p += 16){
    short8 e = *(const short8*)(enc_att + ((size_t)b * P_ + p) * A_ + lane * 8);
    float s = 0.f;
#pragma unroll
    for (int j = 0; j < 8; j++){
      float v = bf2f((unsigned short)e[j]) + dav[j];
      s += fmaxf(v, 0.f) * wfv[j];
    }
#pragma unroll
    for (int off = 32; off > 0; off >>= 1) s += __shfl_down(s, off);
    if (lane == 0) sc[p] = s + bfv;
  }
  __syncthreads();

  // ---- phase 2: softmax over 196 ----
  if (tid < 256) red[tid] = (tid < P_) ? sc[tid] : -1e30f;
  __syncthreads();
  for (int s = 128; s > 0; s >>= 1){ if (tid < s) red[tid] = fmaxf(red[tid], red[tid + s]); __syncthreads(); }
  float mx = red[0];
  __syncthreads();
  float ex = 0.f;
  if (tid < 256){ ex = (tid < P_) ? expf(sc[tid] - mx) : 0.f; red[tid] = ex; }
  __syncthreads();
  for (int s = 128; s > 0; s >>= 1){ if (tid < s) red[tid] += red[tid + s]; __syncthreads(); }
  float inv = 1.f / red[0];
  if (tid < P_) al[tid] = ex * inv;
  __syncthreads();

  // ---- phase 3: awe with 8-way p split, 16B loads ----
  int pg = tid >> 7, et = tid & 127;
  int e0 = bx * 1024 + et * 8;
  const unsigned short* encb = enc_s + (size_t)b * (P_ * ENC_) + e0;
  float aa[8];
#pragma unroll
  for (int j = 0; j < 8; j++) aa[j] = 0.f;
  int pbeg = (pg * 196) >> 3, pend = ((pg + 1) * 196) >> 3;
#pragma unroll 5
  for (int p = pbeg; p < pend; p++){
    float a = al[p];
    short8 v = *(const short8*)(encb + (size_t)p * ENC_);
#pragma unroll
    for (int j = 0; j < 8; j++)
      aa[j] += a * bf2f((unsigned short)v[j]);
  }
#pragma unroll
  for (int j = 0; j < 8; j++) part2[pg][et][j] = aa[j];
  __syncthreads();
  if (pg == 0){
    float s[8];
#pragma unroll
    for (int j = 0; j < 8; j++){
      float acc = 0.f;
#pragma unroll
      for (int g = 0; g < 8; g++) acc += part2[g][et][j];
      s[j] = acc;
    }
    const float* bp = bias_pre + 512 + e0;
    const float* p0 = ppart + (size_t)b * 2560 + 512 + e0;
    short8 r;
#pragma unroll
    for (int j = 0; j < 8; j++){
      float g = bp[j];
#pragma unroll
      for (int z = 0; z < ZPRE; z++) g += p0[(size_t)z * (B_ * 2560) + j];
      r[j] = (short)f2bf(sigf(g) * s[j]);
    }
    *(short8*)(xh + (size_t)b * 3072 + 512 + e0) = r;
  }
  // emb gather for this step's token into xh[:512]
  if (bx == 1 && tid < 512){
    int tok = caps_sorted[b * L_ + t];
    xh[(size_t)b * 3072 + tid] = f2bf(emb[(size_t)tok * E_ + tid]);
  }
}

// ---------------- LSTM pointwise: gates = Σz gpart[z] + bias_g ----------------
__global__ void lstm_kernel(const float* __restrict__ gpart,   // [ZG][128][2048]
                            const float* __restrict__ bias_g,
                            float* __restrict__ h, float* __restrict__ c,
                            unsigned short* __restrict__ h_b, unsigned short* __restrict__ xh,
                            unsigned short* __restrict__ hnew_b,
                            const int* __restrict__ dec_len, int t){
  int idx = blockIdx.x * 256 + threadIdx.x;   // 65536 total
  int b = idx >> 9, d = idx & 511;
  if (t >= dec_len[b]) return;
  const float* gr = gpart + (size_t)b * 2048;
  float i_ = bias_g[d], f_ = bias_g[512 + d], g_ = bias_g[1024 + d], o_ = bias_g[1536 + d];
#pragma unroll
  for (int z = 0; z < ZG; z++){
    const float* gz = gr + (size_t)z * (B_ * 2048);
    i_ += gz[d]; f_ += gz[512 + d]; g_ += gz[1024 + d]; o_ += gz[1536 + d];
  }
  float cn = sigf(f_) * c[idx] + sigf(i_) * tanhf(g_);
  float hn = sigf(o_) * tanhf(cn);
  h[idx] = hn; c[idx] = cn;
  unsigned short hvb = f2bf(hn);
  h_b[idx] = hvb;
  xh[(size_t)b * 3072 + 2560 + d] = hvb;
  hnew_b[(size_t)t * (B_ * D_) + idx] = hvb;
}

// ---------------- preds GEMM: BK=64 core + XCD-rect partition + LDS stores ---
__launch_bounds__(256)
__global__ void gemm_preds(const unsigned short* __restrict__ A,    // hnew_b 6528x512
                           const unsigned short* __restrict__ Bm,   // Wfc_b 10000x512
                           const float* __restrict__ bias,
                           float* __restrict__ Cf,
                           const int* __restrict__ dec_len){
  __shared__ __attribute__((aligned(16))) char smem[4 * 64 * 68 * 4];
  unsigned short* As = (unsigned short*)smem;                 // 128x64 = 16 KB
  unsigned short* Bs = (unsigned short*)(smem + 16384);       // 128x64 = 16 KB
  int bid = blockIdx.x;
  int xcd = bid & 7, i = bid >> 3;          // i in [0,520)
  int mchunk = xcd >> 1, nchunk = xcd & 1;
  int mi_ = i % 13, ni_ = i / 13;
  int mt = mchunk * 13 + mi_;
  int nt = nchunk * 40 + ni_;
  if (mt >= 51 || nt >= 79) return;
  int m0 = mt * 128, n0 = nt * 128;
  int tid = threadIdx.x; int lane = tid & 63; int w = tid >> 6;
  const floatx4 vzero = {0.f,0.f,0.f,0.f};
  floatx4 acc[4][4];
#pragma unroll
  for (int i_ = 0; i_ < 4; i_++)
#pragma unroll
    for (int j_ = 0; j_ < 4; j_++) acc[i_][j_] = vzero;
  int mbase = (w & 1) << 6, nbase = (w >> 1) << 6;
  int fr = lane & 15, fk = (lane >> 4) << 3;
  int rsw = (fr & 7) << 3;
  for (int k0 = 0; k0 < D_; k0 += 64){
#pragma unroll
    for (int r_ = 0; r_ < 4; r_++){
      int chunk = r_ * 256 + tid;
      int row = chunk >> 3, kc = (chunk & 7) << 3;
      short8 av = *(const short8*)(A + (size_t)(m0 + row) * D_ + k0 + kc);
      int bn = n0 + row; if (bn > V_ - 1) bn = V_ - 1;
      short8 bv = *(const short8*)(Bm + (size_t)bn * D_ + k0 + kc);
      int sidx = row * 64 + (kc ^ ((row & 7) << 3));
      *(short8*)&As[sidx] = av;
      *(short8*)&Bs[sidx] = bv;
    }
    __syncthreads();
#pragma unroll
    for (int ks = 0; ks < 2; ks++){
      short8 af[4], bfrag[4];
#pragma unroll
      for (int i_ = 0; i_ < 4; i_++){
        af[i_]    = *(const short8*)&As[(mbase + i_ * 16 + fr) * 64 + ((ks * 32 + fk) ^ rsw)];
        bfrag[i_] = *(const short8*)&Bs[(nbase + i_ * 16 + fr) * 64 + ((ks * 32 + fk) ^ rsw)];
      }
#pragma unroll
      for (int mi = 0; mi < 4; mi++)
#pragma unroll
        for (int ni = 0; ni < 4; ni++)
          acc[mi][ni] = __builtin_amdgcn_mfma_f32_16x16x32_bf16(af[mi], bfrag[ni], acc[mi][ni], 0, 0, 0);
    }
    __syncthreads();
  }
  // stage per-wave 64x64 quadrant into LDS (aliases As/Bs; all reads drained)
  float* Cs = (float*)smem + (size_t)w * (64 * 68);
#pragma unroll
  for (int mi = 0; mi < 4; mi++)
#pragma unroll
    for (int ni = 0; ni < 4; ni++){
      int lc = ni * 16 + fr;
      int col = n0 + nbase + lc;
      float bb = bias[col < V_ ? col : V_ - 1];
#pragma unroll
      for (int r = 0; r < 4; r++){
        int lr = mi * 16 + ((lane >> 4) << 2) + r;
        Cs[lr * 68 + lc] = acc[mi][ni][r] + bb;
      }
    }
#pragma unroll
  for (int rd = 0; rd < 16; rd++){
    int lr = rd * 4 + (lane >> 4);
    int m = m0 + mbase + lr;
    int tt = m >> 7, b = m & 127;
    int col = n0 + nbase + fr * 4;
    floatx4 v = *(const floatx4*)&Cs[lr * 68 + fr * 4];
    if (tt >= dec_len[b]){ v[0] = 0.f; v[1] = 0.f; v[2] = 0.f; v[3] = 0.f; }
    if (col < V_)
      __builtin_nontemporal_store(v, (floatx4*)(Cf + ((size_t)b * T_ + tt) * V_ + col));
  }
}

extern "C" void kernel_launch(void* const* d_in, const int* in_sizes, int n_in,
                              void* d_out, int out_size, void* d_ws, size_t ws_size,
                              hipStream_t stream) {
  const float* encoder_out = (const float*)d_in[0];
  const int*   caps        = (const int*)d_in[1];
  const int*   cap_len     = (const int*)d_in[2];
  const float* emb         = (const float*)d_in[3];
  const float* We          = (const float*)d_in[4];
  const float* be          = (const float*)d_in[5];
  const float* Wd          = (const float*)d_in[6];
  const float* bd          = (const float*)d_in[7];
  const float* wf          = (const float*)d_in[8];
  const float* bf          = (const float*)d_in[9];
  const float* W_ih        = (const float*)d_in[10];
  const float* b_ih        = (const float*)d_in[11];
  const float* W_hh        = (const float*)d_in[12];
  const float* b_hh        = (const float*)d_in[13];
  const float* Wbeta       = (const float*)d_in[14];
  const float* bbeta       = (const float*)d_in[15];
  const float* Wfc         = (const float*)d_in[16];
  const float* bfc         = (const float*)d_in[17];

  float* out_preds  = (float*)d_out;
  float* out_caps   = out_preds + (size_t)B_ * T_ * V_;
  float* out_declen = out_caps + (size_t)B_ * L_;

  char* w = (char*)d_ws;
  auto alloc = [&](size_t bytes) -> void* {
    void* p = (void*)w;
    w += (bytes + 255) & ~(size_t)255;
    return p;
  };
  int*   order       = (int*)alloc(B_ * 4);
  int*   dec_len     = (int*)alloc(B_ * 4);
  int*   nact        = (int*)alloc(64 * 4);
  int*   caps_sorted = (int*)alloc((size_t)B_ * L_ * 4);
  unsigned short* enc_s   = (unsigned short*)alloc((size_t)B_ * P_ * ENC_ * 2);
  unsigned short* We_b    = (unsigned short*)alloc((size_t)512 * 2048 * 2);
  unsigned short* Wpre_b  = (unsigned short*)alloc((size_t)2560 * 512 * 2);
  unsigned short* Wg_b    = (unsigned short*)alloc((size_t)2048 * 3072 * 2);
  unsigned short* Wfc_b   = (unsigned short*)alloc((size_t)10000 * 512 * 2);
  unsigned short* enc_att = (unsigned short*)alloc((size_t)B_ * P_ * A_ * 2);
  float* bias_pre    = (float*)alloc(2560 * 4);
  float* bias_g      = (float*)alloc(2048 * 4);
  float* ppart       = (float*)alloc((size_t)ZPRE * B_ * 2560 * 4);
  float* gpart       = (float*)alloc((size_t)ZG * B_ * 2048 * 4);
  unsigned short* xh = (unsigned short*)alloc((size_t)B_ * 3072 * 2);
  float* h           = (float*)alloc((size_t)B_ * D_ * 4);
  float* c           = (float*)alloc((size_t)B_ * D_ * 4);
  unsigned short* h_b = (unsigned short*)alloc((size_t)B_ * D_ * 2);
  unsigned short* hnew_b = (unsigned short*)alloc((size_t)T_ * B_ * D_ * 2);

  sort_kernel<<<1, 128, 0, stream>>>(cap_len, caps, order, dec_len, caps_sorted,
                                     out_caps, out_declen, nact);
  gather_kernel<<<dim3(392, 128), 256, 0, stream>>>(encoder_out, order, enc_s);
  prep_kernel<<<2048, 256, 0, stream>>>(We, Wd, Wbeta, W_ih, W_hh, Wfc, bd, bbeta, b_ih, b_hh,
                                        We_b, Wpre_b, Wg_b, Wfc_b, bias_pre, bias_g,
                                        h, c, h_b, xh);

  // enc_att = enc_s @ We^T + be -> bf16 : M=25088, N=512, K=2048 (BK=64)
  gemm_encatt<<<dim3(4, 196), 256, 0, stream>>>(enc_s, We_b, be, enc_att);

  for (int t = 0; t < T_; t++){
    // ppart[z] = h @ [Wd;Wbeta]^T  (64-row tiles, BK=128, 1 iter, nact-masked)
    gemm_skinny64<<<dim3(20, 2, ZPRE), 256, 0, stream>>>(
        h_b, D_, Wpre_b, D_, ppart, 2560, 512 / ZPRE, nact, t);

    // attention (sums ppart slices + bias) -> xh = [emb | gate*awe]
    attn_kernel<<<dim3(2, B_), 1024, 0, stream>>>(enc_att, enc_s, ppart, bias_pre, wf, bf,
                                                  emb, caps_sorted, xh, dec_len, t);

    // gpart[z] = xh @ [W_ih|W_hh]^T  (64-row tiles, BK=128, 3 iters, nact-masked)
    gemm_skinny64<<<dim3(16, 2, ZG), 256, 0, stream>>>(
        xh, 3072, Wg_b, 3072, gpart, 2048, 3072 / ZG, nact, t);

    // lstm sums gpart slices + bias_g
    lstm_kernel<<<(B_ * D_) / 256, 256, 0, stream>>>(gpart, bias_g, h, c, h_b, xh, hnew_b,
                                                     dec_len, t);
  }

  // preds: (T*B, V) = hnew @ Wfc^T + bfc, masked + scattered to (B,T,V)
  gemm_preds<<<4160, 256, 0, stream>>>(hnew_b, Wfc_b, bfc, out_preds, dec_len);
}